// Round 3
// baseline (858.639 us; speedup 1.0000x reference)
//
#include <hip/hip_runtime.h>
#include <hip/hip_bf16.h>

// NNConv GNN, round 10: DE-FUSE.
//  R7/R8/R9 post-mortem: all fused variants sit at 40-60k cycles per wave
//  lifetime vs ~5k cy of identifiable work; raising occupancy (R8) raised
//  wave lifetime proportionally -> a serialized per-CU resource (G panel
//  re-streamed through L1 every block: 4608 lines x 1334 blocks) + barrier
//  coupling dominates. The fused design saves the P round-trip (87 MB) but
//  pays 2x more in queue stalls (80 us/layer for 40 MB moved).
//  R10 splits each layer into three streaming kernels:
//   pgemm: P[20000][1088](f32) = h @ G via MFMA, BM=64 nodes/block, no LDS,
//          no barrier; G re-read 1334->313 panels/layer (4.3x less L1 fill).
//          Strip 17 -> Proot as before.
//   edgec: one WAVE per node (20k independent waves): p[17] in registers
//          (17 coalesced loads), slot loop with wave-uniform scalar eks/meta
//          loads + 1-deep prefetch (nothing else on lgkmcnt now).
//   agg:   unchanged.
//  Math order identical to R7-R9 -> absmax should stay 0.125.
//  Workspace: P needs 87 MB on top of ~49 MB fixed; if ws_size is too small
//  we process nodes in 2 or 4 contiguous chunks reusing a smaller P.

#define NN 20000
#define NE 100000
#define WD 64
#define DEPTH 6
#define BM 64            // pgemm node-tile (4 MFMA row-groups)

typedef __attribute__((ext_vector_type(8))) short bf16x8;
typedef __attribute__((ext_vector_type(4))) float f32x4;

__device__ __forceinline__ unsigned short f2bf(float v) {
    union { float f; unsigned u; } x; x.f = v;
    unsigned r = x.u + 0x7fffu + ((x.u >> 16) & 1u);
    return (unsigned short)(r >> 16);
}
__device__ __forceinline__ float bf2f(unsigned short b) {
    union { unsigned u; float f; } x; x.u = ((unsigned)b) << 16;
    return x.f;
}

// ---------------- per-node in/out degree counts ----------------
__global__ __launch_bounds__(256) void count_kernel(const int* __restrict__ ei,
                                                    int* __restrict__ outc,
                                                    int* __restrict__ inc)
{
    int e = blockIdx.x * 256 + threadIdx.x;
    if (e >= NE) return;
    atomicAdd(&outc[ei[e]], 1);
    atomicAdd(&inc[ei[NE + e]], 1);
}

// ---------------- hierarchical scan over [outc | inc] (40000 ints) ----------
__global__ __launch_bounds__(256) void scanA_kernel(const int* __restrict__ cnt,
                                                    int* __restrict__ partials)
{
    int b = blockIdx.x, t = threadIdx.x, lane = t & 63, w = t >> 6;
    int base = b * 1024 + t * 4;
    int s = 0;
#pragma unroll
    for (int i = 0; i < 4; ++i) {
        int idx = base + i;
        if (idx < 2 * NN) s += cnt[idx];
    }
#pragma unroll
    for (int off = 32; off > 0; off >>= 1) s += __shfl_down(s, off, 64);
    __shared__ int wsum[4];
    if (lane == 0) wsum[w] = s;
    __syncthreads();
    if (t == 0) partials[b] = wsum[0] + wsum[1] + wsum[2] + wsum[3];
}

__global__ __launch_bounds__(64) void scanB_kernel(const int* __restrict__ partials,
                                                   int* __restrict__ bases)
{
    int l = threadIdx.x;
    int p = (l < 40) ? partials[l] : 0;
    int v = p;
#pragma unroll
    for (int off = 1; off < 64; off <<= 1) {
        int u = __shfl_up(v, off, 64);
        if (l >= off) v += u;
    }
    if (l < 40) bases[l] = v - p;   // exclusive
}

__global__ __launch_bounds__(256) void scanC_kernel(const int* __restrict__ cnt,
                                                    const int* __restrict__ bases,
                                                    int* __restrict__ rps,
                                                    int* __restrict__ rpd,
                                                    float* __restrict__ invd)
{
    int b = blockIdx.x, t = threadIdx.x, lane = t & 63, w = t >> 6;
    int base = b * 1024 + t * 4;
    int v[4], s = 0;
#pragma unroll
    for (int i = 0; i < 4; ++i) {
        int idx = base + i;
        v[i] = (idx < 2 * NN) ? cnt[idx] : 0;
        s += v[i];
    }
    int tsum = s, sc = s;
#pragma unroll
    for (int off = 1; off < 64; off <<= 1) {
        int u = __shfl_up(sc, off, 64);
        if (lane >= off) sc += u;
    }
    __shared__ int wtot[4];
    if (lane == 63) wtot[w] = sc;
    __syncthreads();
    int wbase = 0;
    for (int j = 0; j < w; ++j) wbase += wtot[j];
    int run = bases[b] + wbase + sc - tsum;
#pragma unroll
    for (int i = 0; i < 4; ++i) {
        int idx = base + i;
        int e = run; run += v[i];
        if (idx < NN) {
            rps[idx] = e;
        } else if (idx < 2 * NN) {
            rpd[idx - NN] = e - NE;           // first-half total == NE
            invd[idx - NN] = 1.0f / fmaxf((float)v[i], 1.0f);
        }
    }
    if (b == 0 && t == 0) { rps[NN] = NE; rpd[NN] = NE; }
}

// ---------------- ek MLP + CSR fill + per-slot meta ----------------
__global__ __launch_bounds__(256) void ekfill_kernel(
    const int* __restrict__ ei, const float* __restrict__ ea,
    const float* __restrict__ k1w, const float* __restrict__ k1b,
    const int* __restrict__ rps, const int* __restrict__ rpd,
    int* __restrict__ fs, int* __restrict__ fd,
    float* __restrict__ eks, int* __restrict__ sdmeta)
{
    int e = blockIdx.x * 256 + threadIdx.x;
    if (e >= NE) return;
    int s = ei[e], d = ei[NE + e];
    float a[6];
#pragma unroll
    for (int i = 0; i < 6; ++i) a[i] = ea[e * 6 + i];
    int slot_s = rps[s] + atomicAdd(&fs[s], 1);
    int slot_d = rpd[d] + atomicAdd(&fd[d], 1);
    sdmeta[slot_s] = slot_d;   // dst-CSR slot for the msg scatter
#pragma unroll
    for (int j = 0; j < 16; ++j) {
        float v = k1b[j];
#pragma unroll
        for (int i = 0; i < 6; ++i) v = fmaf(a[i], k1w[i * 16 + j], v);
        eks[(size_t)slot_s * 16 + j] = fmaxf(v, 0.f);
    }
}

// ---------------- GwT hi/lo bf16, [1152 rows n][64 cols k] -----------------
__global__ __launch_bounds__(256) void gwt_kernel(
    const float* __restrict__ k2w, const float* __restrict__ k2b,
    const float* __restrict__ rootw,
    unsigned short* __restrict__ Gh, unsigned short* __restrict__ Gl)
{
    int idx = blockIdx.x * 256 + threadIdx.x;   // 1152*64
    if (idx >= 1152 * 64) return;
    int n = idx >> 6, k = idx & 63;
    int b = n >> 6, o = n & 63;
    float g;
    if (b < 16)       g = k2w[b * 4096 + k * 64 + o];
    else if (b == 16) g = k2b[k * 64 + o];
    else              g = rootw[k * 64 + o];
    unsigned short hi = f2bf(g);
    Gh[idx] = hi;
    Gl[idx] = f2bf(g - bf2f(hi));
}

// ---------------- h0 = x*fc1_w + fc1_b -> hi/lo bf16 ----------------
__global__ __launch_bounds__(256) void h0_kernel(
    const float* __restrict__ x, const float* __restrict__ w,
    const float* __restrict__ b,
    unsigned short* __restrict__ hhi, unsigned short* __restrict__ hlo)
{
    int idx = blockIdx.x * 256 + threadIdx.x;
    if (idx >= NN * WD) return;
    int n = idx >> 6, o = idx & 63;
    float v = fmaf(x[n], w[o], b[o]);
    unsigned short hi = f2bf(v);
    hhi[idx] = hi;
    hlo[idx] = f2bf(v - bf2f(hi));
}

// ---------------- pgemm: P[n][1088] = h[n] @ G (strips 0..16), strip17->Proot
// BM=64 nodes/block, 8 waves, no LDS, no barrier. Wave w does tiles
// T = w, w+8, ..., 71 where rg = T/18 (node row-group), st = T%18 (strip).
__global__ __launch_bounds__(512) void pgemm_kernel(
    const unsigned short* __restrict__ hhi, const unsigned short* __restrict__ hlo,
    const unsigned short* __restrict__ Gh, const unsigned short* __restrict__ Gl,
    float* __restrict__ P, float* __restrict__ Proot,
    int nbase, int nend)
{
    int n0 = nbase + blockIdx.x * BM;
    int w = threadIdx.x >> 6, l = threadIdx.x & 63;
    int quad = l >> 4, lr = l & 15;

    for (int T = w; T < 72; T += 8) {
        int rg = T / 18, st = T % 18;
        int arow = n0 + rg * 16 + lr;
        if (arow > NN - 1) arow = NN - 1;
        const bf16x8* pah = (const bf16x8*)(hhi + (size_t)arow * 64 + quad * 8);
        const bf16x8* pal = (const bf16x8*)(hlo + (size_t)arow * 64 + quad * 8);
        bf16x8 ah0 = pah[0], ah1 = pah[4];   // k 0..31, 32..63
        bf16x8 al0 = pal[0], al1 = pal[4];

        f32x4 acc[4];
#pragma unroll
        for (int t = 0; t < 4; ++t) acc[t] = (f32x4){0.f, 0.f, 0.f, 0.f};
#pragma unroll
        for (int t = 0; t < 4; ++t) {
            int brow = st * 64 + t * 16 + lr;
            const bf16x8* pbh = (const bf16x8*)(Gh + (size_t)brow * 64 + quad * 8);
            const bf16x8* pbl = (const bf16x8*)(Gl + (size_t)brow * 64 + quad * 8);
            bf16x8 bh0 = pbh[0], bh1 = pbh[4];
            bf16x8 bl0 = pbl[0], bl1 = pbl[4];
            f32x4 a = acc[t];
            a = __builtin_amdgcn_mfma_f32_16x16x32_bf16(ah0, bh0, a, 0, 0, 0);
            a = __builtin_amdgcn_mfma_f32_16x16x32_bf16(ah0, bl0, a, 0, 0, 0);
            a = __builtin_amdgcn_mfma_f32_16x16x32_bf16(al0, bh0, a, 0, 0, 0);
            a = __builtin_amdgcn_mfma_f32_16x16x32_bf16(ah1, bh1, a, 0, 0, 0);
            a = __builtin_amdgcn_mfma_f32_16x16x32_bf16(ah1, bl1, a, 0, 0, 0);
            a = __builtin_amdgcn_mfma_f32_16x16x32_bf16(al1, bh1, a, 0, 0, 0);
            acc[t] = a;
        }
        // C/D layout: col = lane&15, row(in 16-tile) = quad*4 + reg
        if (st < 17) {
#pragma unroll
            for (int t = 0; t < 4; ++t)
#pragma unroll
                for (int r = 0; r < 4; ++r) {
                    int gn = n0 + rg * 16 + quad * 4 + r;
                    if (gn < nend)
                        P[(size_t)(gn - nbase) * 1088 + st * 64 + t * 16 + lr]
                            = acc[t][r];
                }
        } else {
#pragma unroll
            for (int t = 0; t < 4; ++t)
#pragma unroll
                for (int r = 0; r < 4; ++r) {
                    int gn = n0 + rg * 16 + quad * 4 + r;
                    if (gn < nend)
                        Proot[(size_t)gn * 64 + t * 16 + lr] = acc[t][r];
                }
        }
    }
}

// ---------------- edgec: one wave per node; p[17] in regs; slot loop with
// wave-uniform scalar eks/meta loads, 1-deep prefetch (nothing else shares
// lgkmcnt with these s_loads: p[] is vmcnt, FMAs are register-only).
__global__ __launch_bounds__(256, 6) void edgec_kernel(
    const float* __restrict__ P, const float* __restrict__ eks,
    const int* __restrict__ sdmeta, const int* __restrict__ rps,
    float* __restrict__ msg, int nbase, int nend)
{
    int wv = __builtin_amdgcn_readfirstlane(threadIdx.x >> 6);
    int n = nbase + blockIdx.x * 4 + wv;
    if (n >= nend) return;
    int l = threadIdx.x & 63;
    int r0 = rps[n], r1 = rps[n + 1];
    if (r0 >= r1) return;

    const float* Pr = P + (size_t)(n - nbase) * 1088;
    float p[17];
#pragma unroll
    for (int k = 0; k < 17; ++k) p[k] = Pr[k * 64 + l];

    // prologue: load slot r0 (uniform -> scalar path)
    int su = __builtin_amdgcn_readfirstlane(r0);
    const float* er = eks + (size_t)su * 16;
    f32x4 e0 = *(const f32x4*)(er);
    f32x4 e1 = *(const f32x4*)(er + 4);
    f32x4 e2 = *(const f32x4*)(er + 8);
    f32x4 e3 = *(const f32x4*)(er + 12);
    int ds = sdmeta[su];

    for (int s = r0; s < r1; ++s) {
        f32x4 c0 = e0, c1 = e1, c2 = e2, c3 = e3;
        int cds = ds;
        if (s + 1 < r1) {   // prefetch next slot during this slot's FMAs
            int s2 = __builtin_amdgcn_readfirstlane(s + 1);
            const float* er2 = eks + (size_t)s2 * 16;
            e0 = *(const f32x4*)(er2);
            e1 = *(const f32x4*)(er2 + 4);
            e2 = *(const f32x4*)(er2 + 8);
            e3 = *(const f32x4*)(er2 + 12);
            ds = sdmeta[s2];
        }
        float ma = p[16], mb = 0.f;   // two chains for ILP
        ma = fmaf(c0[0], p[0], ma);  mb = fmaf(c0[1], p[1], mb);
        ma = fmaf(c0[2], p[2], ma);  mb = fmaf(c0[3], p[3], mb);
        ma = fmaf(c1[0], p[4], ma);  mb = fmaf(c1[1], p[5], mb);
        ma = fmaf(c1[2], p[6], ma);  mb = fmaf(c1[3], p[7], mb);
        ma = fmaf(c2[0], p[8], ma);  mb = fmaf(c2[1], p[9], mb);
        ma = fmaf(c2[2], p[10], ma); mb = fmaf(c2[3], p[11], mb);
        ma = fmaf(c3[0], p[12], ma); mb = fmaf(c3[1], p[13], mb);
        ma = fmaf(c3[2], p[14], ma); mb = fmaf(c3[3], p[15], mb);
        msg[(size_t)cds * 64 + l] = ma + mb;
    }
}

// ---------------- per-dst sum (coalesced, 4-way ILP) + fused epilogue -------
__global__ __launch_bounds__(256) void agg_kernel(
    const float* __restrict__ msg, const int* __restrict__ rpd,
    const float* __restrict__ invd, const float* __restrict__ Proot,
    const float* __restrict__ convb, float* __restrict__ h,
    unsigned short* __restrict__ hhi, unsigned short* __restrict__ hlo)
{
    int i = blockIdx.x * 4 + (threadIdx.x >> 6);
    if (i >= NN) return;
    int l = threadIdx.x & 63;
    int r0 = rpd[i], r1 = rpd[i + 1];
    float a0 = 0.f, a1 = 0.f, a2 = 0.f, a3 = 0.f;
    int s = r0;
    for (; s + 3 < r1; s += 4) {
        a0 += msg[(size_t)s * 64 + l];
        a1 += msg[(size_t)(s + 1) * 64 + l];
        a2 += msg[(size_t)(s + 2) * 64 + l];
        a3 += msg[(size_t)(s + 3) * 64 + l];
    }
    for (; s < r1; ++s) a0 += msg[(size_t)s * 64 + l];
    float acc = (a0 + a1) + (a2 + a3);
    float v = fmaf(acc, invd[i], Proot[(size_t)i * 64 + l] + convb[l]);
    v = fmaxf(v, 0.f);
    int idx = i * 64 + l;
    h[idx] = v;
    unsigned short hi = f2bf(v);
    hhi[idx] = hi;
    hlo[idx] = f2bf(v - bf2f(hi));
}

// ---------------- out = h @ fc2_w + fc2_b ----------------
__global__ __launch_bounds__(256) void out_kernel(
    const float* __restrict__ h, const float* __restrict__ fc2_w,
    const float* __restrict__ fc2_b, float* __restrict__ out)
{
    int wave = blockIdx.x * 4 + (threadIdx.x >> 6);
    int lane = threadIdx.x & 63;
    float v = h[(size_t)wave * 64 + lane] * fc2_w[lane];
#pragma unroll
    for (int off = 32; off > 0; off >>= 1) v += __shfl_down(v, off);
    if (lane == 0) out[wave] = v + fc2_b[0];
}

extern "C" void kernel_launch(void* const* d_in, const int* in_sizes, int n_in,
                              void* d_out, int out_size, void* d_ws, size_t ws_size,
                              hipStream_t stream)
{
    const float* x         = (const float*)d_in[0];
    const int*   ei        = (const int*)  d_in[1];
    const float* edge_attr = (const float*)d_in[2];
    const float* fc1_w     = (const float*)d_in[3];
    const float* fc1_b     = (const float*)d_in[4];
    const float* k1_w      = (const float*)d_in[5];
    const float* k1_b      = (const float*)d_in[6];
    const float* k2_w      = (const float*)d_in[7];
    const float* k2_b      = (const float*)d_in[8];
    const float* root_w    = (const float*)d_in[9];
    const float* conv_b    = (const float*)d_in[10];
    const float* fc2_w     = (const float*)d_in[11];
    const float* fc2_b     = (const float*)d_in[12];
    float* out = (float*)d_out;

    // workspace layout, f32 units
    float* ws = (float*)d_ws;
    size_t off = 0;
    int* cnt   = (int*)(ws + off); off += 4 * NN;       // outc|inc|fs|fd
    int* outc  = cnt;
    int* inc   = cnt + NN;
    int* fs    = cnt + 2 * NN;
    int* fd    = cnt + 3 * NN;
    int* rps   = (int*)(ws + off); off += 20004;
    int* rpd   = (int*)(ws + off); off += 20004;
    int* partials = (int*)(ws + off); off += 64;
    int* bases    = (int*)(ws + off); off += 64;
    int* sdmeta   = (int*)(ws + off); off += NE + 16;   // dst_slot per src-slot
    float* invd  = ws + off; off += NN;
    float* eks   = ws + off; off += (size_t)NE * 16;
    unsigned short* Gh  = (unsigned short*)(ws + off); off += 36864;
    unsigned short* Gl  = (unsigned short*)(ws + off); off += 36864;
    unsigned short* hhi = (unsigned short*)(ws + off); off += (size_t)NN * 32;
    unsigned short* hlo = (unsigned short*)(ws + off); off += (size_t)NN * 32;
    float* h     = ws + off; off += (size_t)NN * WD;
    float* msg   = ws + off; off += (size_t)NE * WD;
    float* Proot = ws + off; off += (size_t)NN * WD;
    float* P     = ws + off;                            // 1088 f32 per node

    // choose node-chunking so P fits in the remaining workspace
    size_t totalf = ws_size / sizeof(float);
    size_t availf = totalf > off ? totalf - off : 0;
    int nch = 1;
    if (availf < (size_t)NN * 1088)            nch = 2;
    if (nch == 2 && availf < (size_t)(NN / 2) * 1088) nch = 4;
    int csz = NN / nch;                                  // 20000 % 4 == 0

    hipMemsetAsync(cnt, 0, 4 * NN * sizeof(int), stream);
    count_kernel<<<(NE + 255) / 256, 256, 0, stream>>>(ei, outc, inc);
    scanA_kernel<<<40, 256, 0, stream>>>(cnt, partials);
    scanB_kernel<<<1, 64, 0, stream>>>(partials, bases);
    scanC_kernel<<<40, 256, 0, stream>>>(cnt, bases, rps, rpd, invd);
    ekfill_kernel<<<(NE + 255) / 256, 256, 0, stream>>>(ei, edge_attr, k1_w, k1_b,
                                                        rps, rpd, fs, fd, eks, sdmeta);
    gwt_kernel<<<(1152 * 64 + 255) / 256, 256, 0, stream>>>(k2_w, k2_b, root_w, Gh, Gl);
    h0_kernel<<<(NN * WD + 255) / 256, 256, 0, stream>>>(x, fc1_w, fc1_b, hhi, hlo);

    for (int layer = 0; layer < DEPTH; ++layer) {
        for (int c = 0; c < nch; ++c) {
            int nb = c * csz, ne = nb + csz;
            pgemm_kernel<<<(csz + BM - 1) / BM, 512, 0, stream>>>(
                hhi, hlo, Gh, Gl, P, Proot, nb, ne);
            edgec_kernel<<<(csz + 3) / 4, 256, 0, stream>>>(
                P, eks, sdmeta, rps, msg, nb, ne);
        }
        agg_kernel<<<(NN + 3) / 4, 256, 0, stream>>>(msg, rpd, invd, Proot,
                                                     conv_b, h, hhi, hlo);
    }

    out_kernel<<<NN / 4, 256, 0, stream>>>(h, fc2_w, fc2_b, out);
}

// Round 5
// 849.202 us; speedup vs baseline: 1.0111x; 1.0111x over previous
//
#include <hip/hip_runtime.h>
#include <hip/hip_bf16.h>

// NNConv GNN, round 12 (= R11 resubmit after container infra failure).
//  Aggregate-first factorization:
//    agg_i[o] = sum_{c,k} K2[c][k][o] * U_i[c,k],
//    U_i[c,k] = sum_{e->i} ek_e[c] * h[src_e][k]  (+ strip 16 = sum h[src]).
//  ucomp: wave-per-dst-node (full occupancy, no barriers): per edge 17
//         FMAs; U row written once as bf16 hi/lo (dense coalesced stores).
//  ugemm: [20000 x 1088] @ [1088 x 64] split-bf16 MFMA, + 2 k-steps of
//         h @ root_w folded in, epilogue does *invd + conv_b + relu ->
//         h f32 + hhi/hlo. msg, Proot, agg kernel all eliminated.
//  h double-buffered so chunked U (if ws is small) stays correct.
//  Hardening vs R11: chunk selector walks divisors {1,2,4,5,8,10,20} until
//  U fits the remaining workspace (removes any OOB path for small ws).

#define NN 20000
#define NE 100000
#define WD 64
#define DEPTH 6

typedef __attribute__((ext_vector_type(8))) short bf16x8;
typedef __attribute__((ext_vector_type(4))) float f32x4;

__device__ __forceinline__ unsigned short f2bf(float v) {
    union { float f; unsigned u; } x; x.f = v;
    unsigned r = x.u + 0x7fffu + ((x.u >> 16) & 1u);
    return (unsigned short)(r >> 16);
}
__device__ __forceinline__ float bf2f(unsigned short b) {
    union { unsigned u; float f; } x; x.u = ((unsigned)b) << 16;
    return x.f;
}

// ---------------- per-node in/out degree counts ----------------
__global__ __launch_bounds__(256) void count_kernel(const int* __restrict__ ei,
                                                    int* __restrict__ outc,
                                                    int* __restrict__ inc)
{
    int e = blockIdx.x * 256 + threadIdx.x;
    if (e >= NE) return;
    atomicAdd(&outc[ei[e]], 1);
    atomicAdd(&inc[ei[NE + e]], 1);
}

// ---------------- hierarchical scan over [outc | inc] (40000 ints) ----------
__global__ __launch_bounds__(256) void scanA_kernel(const int* __restrict__ cnt,
                                                    int* __restrict__ partials)
{
    int b = blockIdx.x, t = threadIdx.x, lane = t & 63, w = t >> 6;
    int base = b * 1024 + t * 4;
    int s = 0;
#pragma unroll
    for (int i = 0; i < 4; ++i) {
        int idx = base + i;
        if (idx < 2 * NN) s += cnt[idx];
    }
#pragma unroll
    for (int off = 32; off > 0; off >>= 1) s += __shfl_down(s, off, 64);
    __shared__ int wsum[4];
    if (lane == 0) wsum[w] = s;
    __syncthreads();
    if (t == 0) partials[b] = wsum[0] + wsum[1] + wsum[2] + wsum[3];
}

__global__ __launch_bounds__(64) void scanB_kernel(const int* __restrict__ partials,
                                                   int* __restrict__ bases)
{
    int l = threadIdx.x;
    int p = (l < 40) ? partials[l] : 0;
    int v = p;
#pragma unroll
    for (int off = 1; off < 64; off <<= 1) {
        int u = __shfl_up(v, off, 64);
        if (l >= off) v += u;
    }
    if (l < 40) bases[l] = v - p;   // exclusive
}

__global__ __launch_bounds__(256) void scanC_kernel(const int* __restrict__ cnt,
                                                    const int* __restrict__ bases,
                                                    int* __restrict__ rps,
                                                    int* __restrict__ rpd,
                                                    float* __restrict__ invd)
{
    int b = blockIdx.x, t = threadIdx.x, lane = t & 63, w = t >> 6;
    int base = b * 1024 + t * 4;
    int v[4], s = 0;
#pragma unroll
    for (int i = 0; i < 4; ++i) {
        int idx = base + i;
        v[i] = (idx < 2 * NN) ? cnt[idx] : 0;
        s += v[i];
    }
    int tsum = s, sc = s;
#pragma unroll
    for (int off = 1; off < 64; off <<= 1) {
        int u = __shfl_up(sc, off, 64);
        if (lane >= off) sc += u;
    }
    __shared__ int wtot[4];
    if (lane == 63) wtot[w] = sc;
    __syncthreads();
    int wbase = 0;
    for (int j = 0; j < w; ++j) wbase += wtot[j];
    int run = bases[b] + wbase + sc - tsum;
#pragma unroll
    for (int i = 0; i < 4; ++i) {
        int idx = base + i;
        int e = run; run += v[i];
        if (idx < NN) {
            rps[idx] = e;
        } else if (idx < 2 * NN) {
            rpd[idx - NN] = e - NE;           // first-half total == NE
            invd[idx - NN] = 1.0f / fmaxf((float)v[i], 1.0f);
        }
    }
    if (b == 0 && t == 0) { rps[NN] = NE; rpd[NN] = NE; }
}

// ---------------- ek MLP into dst-CSR slots + src id per slot ----------------
__global__ __launch_bounds__(256) void ekfill_kernel(
    const int* __restrict__ ei, const float* __restrict__ ea,
    const float* __restrict__ k1w, const float* __restrict__ k1b,
    const int* __restrict__ rpd, int* __restrict__ fd,
    float* __restrict__ eks, int* __restrict__ smeta)
{
    int e = blockIdx.x * 256 + threadIdx.x;
    if (e >= NE) return;
    int s = ei[e], d = ei[NE + e];
    float a[6];
#pragma unroll
    for (int i = 0; i < 6; ++i) a[i] = ea[e * 6 + i];
    int slot_d = rpd[d] + atomicAdd(&fd[d], 1);
    smeta[slot_d] = s;                 // src node for this dst-CSR slot
#pragma unroll
    for (int j = 0; j < 16; ++j) {
        float v = k1b[j];
#pragma unroll
        for (int i = 0; i < 6; ++i) v = fmaf(a[i], k1w[i * 16 + j], v);
        eks[(size_t)slot_d * 16 + j] = fmaxf(v, 0.f);
    }
}

// ---------------- K2q[o][1088] / Rq[o][64] bf16 hi/lo (o-major for B-frags) --
__global__ __launch_bounds__(256) void gwt2_kernel(
    const float* __restrict__ k2w, const float* __restrict__ k2b,
    const float* __restrict__ rootw,
    unsigned short* __restrict__ K2qh, unsigned short* __restrict__ K2ql,
    unsigned short* __restrict__ Rqh, unsigned short* __restrict__ Rql)
{
    int idx = blockIdx.x * 256 + threadIdx.x;
    if (idx >= 64 * 1152) return;
    int o = idx / 1152, j = idx - o * 1152;
    float g;
    if (j < 1024)      { int c = j >> 6, k = j & 63; g = k2w[c * 4096 + k * 64 + o]; }
    else if (j < 1088) { int k = j - 1024;           g = k2b[k * 64 + o]; }
    else               { int k = j - 1088;           g = rootw[k * 64 + o]; }
    unsigned short hi = f2bf(g);
    unsigned short lo = f2bf(g - bf2f(hi));
    if (j < 1088) { K2qh[o * 1088 + j] = hi; K2ql[o * 1088 + j] = lo; }
    else { int k = j - 1088; Rqh[o * 64 + k] = hi; Rql[o * 64 + k] = lo; }
}

// ---------------- h0 = x*fc1_w + fc1_b -> f32 + hi/lo bf16 ----------------
__global__ __launch_bounds__(256) void h0_kernel(
    const float* __restrict__ x, const float* __restrict__ w,
    const float* __restrict__ b, float* __restrict__ h,
    unsigned short* __restrict__ hhi, unsigned short* __restrict__ hlo)
{
    int idx = blockIdx.x * 256 + threadIdx.x;
    if (idx >= NN * WD) return;
    int n = idx >> 6, o = idx & 63;
    float v = fmaf(x[n], w[o], b[o]);
    h[idx] = v;
    unsigned short hi = f2bf(v);
    hhi[idx] = hi;
    hlo[idx] = f2bf(v - bf2f(hi));
}

// ---------------- ucomp: U_i[c*64+k] = sum_e ek_e[c]*h[src_e][k]; strip16=sum h
// One wave per dst node; eks/smeta via wave-uniform scalar loads (1-deep
// prefetch); h row gather is a coalesced 256B load (h is 5 MB -> L2).
__global__ __launch_bounds__(256) void ucomp_kernel(
    const float* __restrict__ h, const float* __restrict__ eks,
    const int* __restrict__ smeta, const int* __restrict__ rpd,
    unsigned short* __restrict__ Uhi, unsigned short* __restrict__ Ulo,
    int nbase, int nend)
{
    int wv = threadIdx.x >> 6;
    int i = nbase + blockIdx.x * 4 + wv;
    if (i >= nend) return;
    int l = threadIdx.x & 63;
    float acc[17];
#pragma unroll
    for (int c = 0; c < 17; ++c) acc[c] = 0.f;
    int r0 = rpd[i], r1 = rpd[i + 1];
    if (r0 < r1) {
        int su = __builtin_amdgcn_readfirstlane(r0);
        float hv = h[(size_t)smeta[su] * 64 + l];
        const float* er = eks + (size_t)su * 16;
        f32x4 e0 = *(const f32x4*)(er);
        f32x4 e1 = *(const f32x4*)(er + 4);
        f32x4 e2 = *(const f32x4*)(er + 8);
        f32x4 e3 = *(const f32x4*)(er + 12);
        for (int s = r0; s < r1; ++s) {
            float ch = hv;
            f32x4 c0 = e0, c1 = e1, c2 = e2, c3 = e3;
            if (s + 1 < r1) {   // prefetch next edge during this edge's FMAs
                int s2 = __builtin_amdgcn_readfirstlane(s + 1);
                hv = h[(size_t)smeta[s2] * 64 + l];
                const float* er2 = eks + (size_t)s2 * 16;
                e0 = *(const f32x4*)(er2);
                e1 = *(const f32x4*)(er2 + 4);
                e2 = *(const f32x4*)(er2 + 8);
                e3 = *(const f32x4*)(er2 + 12);
            }
            acc[0]  = fmaf(c0[0], ch, acc[0]);
            acc[1]  = fmaf(c0[1], ch, acc[1]);
            acc[2]  = fmaf(c0[2], ch, acc[2]);
            acc[3]  = fmaf(c0[3], ch, acc[3]);
            acc[4]  = fmaf(c1[0], ch, acc[4]);
            acc[5]  = fmaf(c1[1], ch, acc[5]);
            acc[6]  = fmaf(c1[2], ch, acc[6]);
            acc[7]  = fmaf(c1[3], ch, acc[7]);
            acc[8]  = fmaf(c2[0], ch, acc[8]);
            acc[9]  = fmaf(c2[1], ch, acc[9]);
            acc[10] = fmaf(c2[2], ch, acc[10]);
            acc[11] = fmaf(c2[3], ch, acc[11]);
            acc[12] = fmaf(c3[0], ch, acc[12]);
            acc[13] = fmaf(c3[1], ch, acc[13]);
            acc[14] = fmaf(c3[2], ch, acc[14]);
            acc[15] = fmaf(c3[3], ch, acc[15]);
            acc[16] += ch;
        }
    }
    size_t ub = (size_t)(i - nbase) * 1088 + l;
#pragma unroll
    for (int c = 0; c < 17; ++c) {
        unsigned short hi = f2bf(acc[c]);
        Uhi[ub + c * 64] = hi;
        Ulo[ub + c * 64] = f2bf(acc[c] - bf2f(hi));
    }
}

// ---------------- ugemm: h_out = relu((U @ K2q)*invd + h_in@rootw + convb) ---
// 64 nodes/block, 8 waves; wave w: row-group rg = w>>1, col-tiles (w&1), (w&1)+2.
// No LDS, no barrier; A (U) streams from HBM, B (K2q, 278 KB) L2-resident.
__global__ __launch_bounds__(512) void ugemm_kernel(
    const unsigned short* __restrict__ Uhi, const unsigned short* __restrict__ Ulo,
    const unsigned short* __restrict__ K2qh, const unsigned short* __restrict__ K2ql,
    const unsigned short* __restrict__ Rqh, const unsigned short* __restrict__ Rql,
    const unsigned short* __restrict__ hhi_in, const unsigned short* __restrict__ hlo_in,
    const float* __restrict__ invd, const float* __restrict__ convb,
    float* __restrict__ h_out, unsigned short* __restrict__ hhi_out,
    unsigned short* __restrict__ hlo_out, int nbase, int nend)
{
    int w = threadIdx.x >> 6, l = threadIdx.x & 63;
    int quad = l >> 4, lr = l & 15;
    int rg = w >> 1;
    int n0 = nbase + blockIdx.x * 64;
    int row = n0 + rg * 16 + lr;
    if (row > nend - 1) row = nend - 1;
    const unsigned short* pau = Uhi + (size_t)(row - nbase) * 1088 + quad * 8;
    const unsigned short* pal = Ulo + (size_t)(row - nbase) * 1088 + quad * 8;
    int o0 = (w & 1) * 16 + lr;
    const unsigned short* pb0h = K2qh + (size_t)o0 * 1088 + quad * 8;
    const unsigned short* pb0l = K2ql + (size_t)o0 * 1088 + quad * 8;
    const unsigned short* pb1h = K2qh + (size_t)(o0 + 32) * 1088 + quad * 8;
    const unsigned short* pb1l = K2ql + (size_t)(o0 + 32) * 1088 + quad * 8;
    f32x4 a0 = {0.f, 0.f, 0.f, 0.f}, a1 = {0.f, 0.f, 0.f, 0.f};
#pragma unroll 4
    for (int ks = 0; ks < 34; ++ks) {
        bf16x8 ah  = *(const bf16x8*)(pau + ks * 32);
        bf16x8 av  = *(const bf16x8*)(pal + ks * 32);
        bf16x8 b0h = *(const bf16x8*)(pb0h + ks * 32);
        bf16x8 b0l = *(const bf16x8*)(pb0l + ks * 32);
        bf16x8 b1h = *(const bf16x8*)(pb1h + ks * 32);
        bf16x8 b1l = *(const bf16x8*)(pb1l + ks * 32);
        a0 = __builtin_amdgcn_mfma_f32_16x16x32_bf16(ah, b0h, a0, 0, 0, 0);
        a0 = __builtin_amdgcn_mfma_f32_16x16x32_bf16(ah, b0l, a0, 0, 0, 0);
        a0 = __builtin_amdgcn_mfma_f32_16x16x32_bf16(av, b0h, a0, 0, 0, 0);
        a1 = __builtin_amdgcn_mfma_f32_16x16x32_bf16(ah, b1h, a1, 0, 0, 0);
        a1 = __builtin_amdgcn_mfma_f32_16x16x32_bf16(ah, b1l, a1, 0, 0, 0);
        a1 = __builtin_amdgcn_mfma_f32_16x16x32_bf16(av, b1h, a1, 0, 0, 0);
    }
    // root term: h_in @ rootw (NOT divided by deg)
    f32x4 r0a = {0.f, 0.f, 0.f, 0.f}, r1a = {0.f, 0.f, 0.f, 0.f};
    const unsigned short* prh = hhi_in + (size_t)row * 64 + quad * 8;
    const unsigned short* prl = hlo_in + (size_t)row * 64 + quad * 8;
#pragma unroll
    for (int ks = 0; ks < 2; ++ks) {
        bf16x8 ah  = *(const bf16x8*)(prh + ks * 32);
        bf16x8 av  = *(const bf16x8*)(prl + ks * 32);
        bf16x8 b0h = *(const bf16x8*)(Rqh + (size_t)o0 * 64 + ks * 32 + quad * 8);
        bf16x8 b0l = *(const bf16x8*)(Rql + (size_t)o0 * 64 + ks * 32 + quad * 8);
        bf16x8 b1h = *(const bf16x8*)(Rqh + (size_t)(o0 + 32) * 64 + ks * 32 + quad * 8);
        bf16x8 b1l = *(const bf16x8*)(Rql + (size_t)(o0 + 32) * 64 + ks * 32 + quad * 8);
        r0a = __builtin_amdgcn_mfma_f32_16x16x32_bf16(ah, b0h, r0a, 0, 0, 0);
        r0a = __builtin_amdgcn_mfma_f32_16x16x32_bf16(ah, b0l, r0a, 0, 0, 0);
        r0a = __builtin_amdgcn_mfma_f32_16x16x32_bf16(av, b0h, r0a, 0, 0, 0);
        r1a = __builtin_amdgcn_mfma_f32_16x16x32_bf16(ah, b1h, r1a, 0, 0, 0);
        r1a = __builtin_amdgcn_mfma_f32_16x16x32_bf16(ah, b1l, r1a, 0, 0, 0);
        r1a = __builtin_amdgcn_mfma_f32_16x16x32_bf16(av, b1h, r1a, 0, 0, 0);
    }
    float cb0 = convb[o0], cb1 = convb[o0 + 32];
    // C/D layout: col = lane&15, row = quad*4 + r
#pragma unroll
    for (int r = 0; r < 4; ++r) {
        int gn = n0 + rg * 16 + quad * 4 + r;
        if (gn < nend) {
            float iv = invd[gn];
            size_t idx0 = (size_t)gn * 64 + o0;
            float v0 = fmaf(a0[r], iv, r0a[r] + cb0);
            v0 = fmaxf(v0, 0.f);
            h_out[idx0] = v0;
            unsigned short x0 = f2bf(v0);
            hhi_out[idx0] = x0;
            hlo_out[idx0] = f2bf(v0 - bf2f(x0));
            size_t idx1 = idx0 + 32;
            float v1 = fmaf(a1[r], iv, r1a[r] + cb1);
            v1 = fmaxf(v1, 0.f);
            h_out[idx1] = v1;
            unsigned short x1 = f2bf(v1);
            hhi_out[idx1] = x1;
            hlo_out[idx1] = f2bf(v1 - bf2f(x1));
        }
    }
}

// ---------------- out = h @ fc2_w + fc2_b ----------------
__global__ __launch_bounds__(256) void out_kernel(
    const float* __restrict__ h, const float* __restrict__ fc2_w,
    const float* __restrict__ fc2_b, float* __restrict__ out)
{
    int wave = blockIdx.x * 4 + (threadIdx.x >> 6);
    int lane = threadIdx.x & 63;
    float v = h[(size_t)wave * 64 + lane] * fc2_w[lane];
#pragma unroll
    for (int off = 32; off > 0; off >>= 1) v += __shfl_down(v, off);
    if (lane == 0) out[wave] = v + fc2_b[0];
}

extern "C" void kernel_launch(void* const* d_in, const int* in_sizes, int n_in,
                              void* d_out, int out_size, void* d_ws, size_t ws_size,
                              hipStream_t stream)
{
    const float* x         = (const float*)d_in[0];
    const int*   ei        = (const int*)  d_in[1];
    const float* edge_attr = (const float*)d_in[2];
    const float* fc1_w     = (const float*)d_in[3];
    const float* fc1_b     = (const float*)d_in[4];
    const float* k1_w      = (const float*)d_in[5];
    const float* k1_b      = (const float*)d_in[6];
    const float* k2_w      = (const float*)d_in[7];
    const float* k2_b      = (const float*)d_in[8];
    const float* root_w    = (const float*)d_in[9];
    const float* conv_b    = (const float*)d_in[10];
    const float* fc2_w     = (const float*)d_in[11];
    const float* fc2_b     = (const float*)d_in[12];
    float* out = (float*)d_out;

    // workspace layout, f32 units (all chunk sizes multiples of 4 -> 16B align)
    float* ws = (float*)d_ws;
    size_t off = 0;
    int* cnt   = (int*)(ws + off); off += 4 * NN;       // outc|inc|fs|fd
    int* outc  = cnt;
    int* inc   = cnt + NN;
    int* fd    = cnt + 3 * NN;
    int* rps   = (int*)(ws + off); off += 20004;
    int* rpd   = (int*)(ws + off); off += 20004;
    int* partials = (int*)(ws + off); off += 64;
    int* bases    = (int*)(ws + off); off += 64;
    int* smeta    = (int*)(ws + off); off += NE + 16;   // src node per dst-slot
    float* invd  = ws + off; off += NN;
    float* eks   = ws + off; off += (size_t)NE * 16;
    unsigned short* K2qh = (unsigned short*)(ws + off); off += 34816;  // 64x1088
    unsigned short* K2ql = (unsigned short*)(ws + off); off += 34816;
    unsigned short* Rqh  = (unsigned short*)(ws + off); off += 2048;   // 64x64
    unsigned short* Rql  = (unsigned short*)(ws + off); off += 2048;
    float* hA    = ws + off; off += (size_t)NN * WD;
    float* hB    = ws + off; off += (size_t)NN * WD;
    unsigned short* hhiA = (unsigned short*)(ws + off); off += (size_t)NN * 32;
    unsigned short* hloA = (unsigned short*)(ws + off); off += (size_t)NN * 32;
    unsigned short* hhiB = (unsigned short*)(ws + off); off += (size_t)NN * 32;
    unsigned short* hloB = (unsigned short*)(ws + off); off += (size_t)NN * 32;

    // U chunking (bf16 hi/lo planes, csz*1088 f32 units total)
    size_t totalf = ws_size / sizeof(float);
    size_t availf = totalf > off ? totalf - off : 0;
    const int divs[] = {1, 2, 4, 5, 8, 10, 20};
    int nch = 20;
    for (int di = 0; di < 7; ++di) {
        if (availf >= (size_t)(NN / divs[di]) * 1088) { nch = divs[di]; break; }
    }
    int csz = NN / nch;
    unsigned short* Uhi = (unsigned short*)(ws + off);
    unsigned short* Ulo = (unsigned short*)(ws + off + (size_t)csz * 544);

    hipMemsetAsync(cnt, 0, 4 * NN * sizeof(int), stream);
    count_kernel<<<(NE + 255) / 256, 256, 0, stream>>>(ei, outc, inc);
    scanA_kernel<<<40, 256, 0, stream>>>(cnt, partials);
    scanB_kernel<<<1, 64, 0, stream>>>(partials, bases);
    scanC_kernel<<<40, 256, 0, stream>>>(cnt, bases, rps, rpd, invd);
    ekfill_kernel<<<(NE + 255) / 256, 256, 0, stream>>>(ei, edge_attr, k1_w, k1_b,
                                                        rpd, fd, eks, smeta);
    gwt2_kernel<<<(64 * 1152 + 255) / 256, 256, 0, stream>>>(k2_w, k2_b, root_w,
                                                             K2qh, K2ql, Rqh, Rql);
    h0_kernel<<<(NN * WD + 255) / 256, 256, 0, stream>>>(x, fc1_w, fc1_b,
                                                         hA, hhiA, hloA);

    const float* hin = hA; float* hout = hB;
    const unsigned short* hhin = hhiA; const unsigned short* hloin = hloA;
    unsigned short* hhout = hhiB; unsigned short* hloout = hloB;
    for (int layer = 0; layer < DEPTH; ++layer) {
        for (int c = 0; c < nch; ++c) {
            int nb = c * csz, ne2 = nb + csz;
            ucomp_kernel<<<(csz + 3) / 4, 256, 0, stream>>>(
                hin, eks, smeta, rpd, Uhi, Ulo, nb, ne2);
            ugemm_kernel<<<(csz + 63) / 64, 512, 0, stream>>>(
                Uhi, Ulo, K2qh, K2ql, Rqh, Rql, hhin, hloin, invd, conv_b,
                hout, hhout, hloout, nb, ne2);
        }
        const float* t0 = hin; hin = hout; hout = (float*)t0;
        const unsigned short* t1 = hhin; hhin = hhout; hhout = (unsigned short*)t1;
        const unsigned short* t2 = hloin; hloin = hloout; hloout = (unsigned short*)t2;
    }

    out_kernel<<<NN / 4, 256, 0, stream>>>(hin, fc2_w, fc2_b, out);
}

// Round 6
// 756.808 us; speedup vs baseline: 1.1346x; 1.1221x over previous
//
#include <hip/hip_runtime.h>
#include <hip/hip_bf16.h>

// NNConv GNN, round 13: fix ugemm's latency exposure.
//  R12 post-mortem: aggregate-first factorization works (ucomp ~30us, total
//  traffic ~100 MB/layer) but ugemm ran 104us vs ~16us roofline because
//  (a) VGPR_Count=40 — compiler targeted 8 waves/EU and could only keep ~2
//      loads in flight, serializing ~3 HBM latencies per k-iteration;
//  (b) grid was 313 blocks on 256 CUs — 2x tail imbalance, 16% occupancy.
//  R13 ugemm: 16 rows/block (1250 blocks, tail 1.02x), 256 threads = 4
//  waves, each wave one 16-wide col-tile; k-loop FULLY unrolled (all loads
//  are base+imm straight-line, offsets <= 2112 B) with
//  __launch_bounds__(256,4) (VGPR cap 128) so LLVM can hoist 15-25 loads
//  ahead of the serial MFMA chain. Everything else unchanged from R12.

#define NN 20000
#define NE 100000
#define WD 64
#define DEPTH 6

typedef __attribute__((ext_vector_type(8))) short bf16x8;
typedef __attribute__((ext_vector_type(4))) float f32x4;

__device__ __forceinline__ unsigned short f2bf(float v) {
    union { float f; unsigned u; } x; x.f = v;
    unsigned r = x.u + 0x7fffu + ((x.u >> 16) & 1u);
    return (unsigned short)(r >> 16);
}
__device__ __forceinline__ float bf2f(unsigned short b) {
    union { unsigned u; float f; } x; x.u = ((unsigned)b) << 16;
    return x.f;
}

// ---------------- per-node in/out degree counts ----------------
__global__ __launch_bounds__(256) void count_kernel(const int* __restrict__ ei,
                                                    int* __restrict__ outc,
                                                    int* __restrict__ inc)
{
    int e = blockIdx.x * 256 + threadIdx.x;
    if (e >= NE) return;
    atomicAdd(&outc[ei[e]], 1);
    atomicAdd(&inc[ei[NE + e]], 1);
}

// ---------------- hierarchical scan over [outc | inc] (40000 ints) ----------
__global__ __launch_bounds__(256) void scanA_kernel(const int* __restrict__ cnt,
                                                    int* __restrict__ partials)
{
    int b = blockIdx.x, t = threadIdx.x, lane = t & 63, w = t >> 6;
    int base = b * 1024 + t * 4;
    int s = 0;
#pragma unroll
    for (int i = 0; i < 4; ++i) {
        int idx = base + i;
        if (idx < 2 * NN) s += cnt[idx];
    }
#pragma unroll
    for (int off = 32; off > 0; off >>= 1) s += __shfl_down(s, off, 64);
    __shared__ int wsum[4];
    if (lane == 0) wsum[w] = s;
    __syncthreads();
    if (t == 0) partials[b] = wsum[0] + wsum[1] + wsum[2] + wsum[3];
}

__global__ __launch_bounds__(64) void scanB_kernel(const int* __restrict__ partials,
                                                   int* __restrict__ bases)
{
    int l = threadIdx.x;
    int p = (l < 40) ? partials[l] : 0;
    int v = p;
#pragma unroll
    for (int off = 1; off < 64; off <<= 1) {
        int u = __shfl_up(v, off, 64);
        if (l >= off) v += u;
    }
    if (l < 40) bases[l] = v - p;   // exclusive
}

__global__ __launch_bounds__(256) void scanC_kernel(const int* __restrict__ cnt,
                                                    const int* __restrict__ bases,
                                                    int* __restrict__ rps,
                                                    int* __restrict__ rpd,
                                                    float* __restrict__ invd)
{
    int b = blockIdx.x, t = threadIdx.x, lane = t & 63, w = t >> 6;
    int base = b * 1024 + t * 4;
    int v[4], s = 0;
#pragma unroll
    for (int i = 0; i < 4; ++i) {
        int idx = base + i;
        v[i] = (idx < 2 * NN) ? cnt[idx] : 0;
        s += v[i];
    }
    int tsum = s, sc = s;
#pragma unroll
    for (int off = 1; off < 64; off <<= 1) {
        int u = __shfl_up(sc, off, 64);
        if (lane >= off) sc += u;
    }
    __shared__ int wtot[4];
    if (lane == 63) wtot[w] = sc;
    __syncthreads();
    int wbase = 0;
    for (int j = 0; j < w; ++j) wbase += wtot[j];
    int run = bases[b] + wbase + sc - tsum;
#pragma unroll
    for (int i = 0; i < 4; ++i) {
        int idx = base + i;
        int e = run; run += v[i];
        if (idx < NN) {
            rps[idx] = e;
        } else if (idx < 2 * NN) {
            rpd[idx - NN] = e - NE;           // first-half total == NE
            invd[idx - NN] = 1.0f / fmaxf((float)v[i], 1.0f);
        }
    }
    if (b == 0 && t == 0) { rps[NN] = NE; rpd[NN] = NE; }
}

// ---------------- ek MLP into dst-CSR slots + src id per slot ----------------
__global__ __launch_bounds__(256) void ekfill_kernel(
    const int* __restrict__ ei, const float* __restrict__ ea,
    const float* __restrict__ k1w, const float* __restrict__ k1b,
    const int* __restrict__ rpd, int* __restrict__ fd,
    float* __restrict__ eks, int* __restrict__ smeta)
{
    int e = blockIdx.x * 256 + threadIdx.x;
    if (e >= NE) return;
    int s = ei[e], d = ei[NE + e];
    float a[6];
#pragma unroll
    for (int i = 0; i < 6; ++i) a[i] = ea[e * 6 + i];
    int slot_d = rpd[d] + atomicAdd(&fd[d], 1);
    smeta[slot_d] = s;                 // src node for this dst-CSR slot
#pragma unroll
    for (int j = 0; j < 16; ++j) {
        float v = k1b[j];
#pragma unroll
        for (int i = 0; i < 6; ++i) v = fmaf(a[i], k1w[i * 16 + j], v);
        eks[(size_t)slot_d * 16 + j] = fmaxf(v, 0.f);
    }
}

// ---------------- K2q[o][1088] / Rq[o][64] bf16 hi/lo (o-major for B-frags) --
__global__ __launch_bounds__(256) void gwt2_kernel(
    const float* __restrict__ k2w, const float* __restrict__ k2b,
    const float* __restrict__ rootw,
    unsigned short* __restrict__ K2qh, unsigned short* __restrict__ K2ql,
    unsigned short* __restrict__ Rqh, unsigned short* __restrict__ Rql)
{
    int idx = blockIdx.x * 256 + threadIdx.x;
    if (idx >= 64 * 1152) return;
    int o = idx / 1152, j = idx - o * 1152;
    float g;
    if (j < 1024)      { int c = j >> 6, k = j & 63; g = k2w[c * 4096 + k * 64 + o]; }
    else if (j < 1088) { int k = j - 1024;           g = k2b[k * 64 + o]; }
    else               { int k = j - 1088;           g = rootw[k * 64 + o]; }
    unsigned short hi = f2bf(g);
    unsigned short lo = f2bf(g - bf2f(hi));
    if (j < 1088) { K2qh[o * 1088 + j] = hi; K2ql[o * 1088 + j] = lo; }
    else { int k = j - 1088; Rqh[o * 64 + k] = hi; Rql[o * 64 + k] = lo; }
}

// ---------------- h0 = x*fc1_w + fc1_b -> f32 + hi/lo bf16 ----------------
__global__ __launch_bounds__(256) void h0_kernel(
    const float* __restrict__ x, const float* __restrict__ w,
    const float* __restrict__ b, float* __restrict__ h,
    unsigned short* __restrict__ hhi, unsigned short* __restrict__ hlo)
{
    int idx = blockIdx.x * 256 + threadIdx.x;
    if (idx >= NN * WD) return;
    int n = idx >> 6, o = idx & 63;
    float v = fmaf(x[n], w[o], b[o]);
    h[idx] = v;
    unsigned short hi = f2bf(v);
    hhi[idx] = hi;
    hlo[idx] = f2bf(v - bf2f(hi));
}

// ---------------- ucomp: U_i[c*64+k] = sum_e ek_e[c]*h[src_e][k]; strip16=sum h
// One wave per dst node; eks/smeta via wave-uniform scalar loads (1-deep
// prefetch); h row gather is a coalesced 256B load (h is 5 MB -> L2).
__global__ __launch_bounds__(256) void ucomp_kernel(
    const float* __restrict__ h, const float* __restrict__ eks,
    const int* __restrict__ smeta, const int* __restrict__ rpd,
    unsigned short* __restrict__ Uhi, unsigned short* __restrict__ Ulo,
    int nbase, int nend)
{
    int wv = threadIdx.x >> 6;
    int i = nbase + blockIdx.x * 4 + wv;
    if (i >= nend) return;
    int l = threadIdx.x & 63;
    float acc[17];
#pragma unroll
    for (int c = 0; c < 17; ++c) acc[c] = 0.f;
    int r0 = rpd[i], r1 = rpd[i + 1];
    if (r0 < r1) {
        int su = __builtin_amdgcn_readfirstlane(r0);
        float hv = h[(size_t)smeta[su] * 64 + l];
        const float* er = eks + (size_t)su * 16;
        f32x4 e0 = *(const f32x4*)(er);
        f32x4 e1 = *(const f32x4*)(er + 4);
        f32x4 e2 = *(const f32x4*)(er + 8);
        f32x4 e3 = *(const f32x4*)(er + 12);
        for (int s = r0; s < r1; ++s) {
            float ch = hv;
            f32x4 c0 = e0, c1 = e1, c2 = e2, c3 = e3;
            if (s + 1 < r1) {   // prefetch next edge during this edge's FMAs
                int s2 = __builtin_amdgcn_readfirstlane(s + 1);
                hv = h[(size_t)smeta[s2] * 64 + l];
                const float* er2 = eks + (size_t)s2 * 16;
                e0 = *(const f32x4*)(er2);
                e1 = *(const f32x4*)(er2 + 4);
                e2 = *(const f32x4*)(er2 + 8);
                e3 = *(const f32x4*)(er2 + 12);
            }
            acc[0]  = fmaf(c0[0], ch, acc[0]);
            acc[1]  = fmaf(c0[1], ch, acc[1]);
            acc[2]  = fmaf(c0[2], ch, acc[2]);
            acc[3]  = fmaf(c0[3], ch, acc[3]);
            acc[4]  = fmaf(c1[0], ch, acc[4]);
            acc[5]  = fmaf(c1[1], ch, acc[5]);
            acc[6]  = fmaf(c1[2], ch, acc[6]);
            acc[7]  = fmaf(c1[3], ch, acc[7]);
            acc[8]  = fmaf(c2[0], ch, acc[8]);
            acc[9]  = fmaf(c2[1], ch, acc[9]);
            acc[10] = fmaf(c2[2], ch, acc[10]);
            acc[11] = fmaf(c2[3], ch, acc[11]);
            acc[12] = fmaf(c3[0], ch, acc[12]);
            acc[13] = fmaf(c3[1], ch, acc[13]);
            acc[14] = fmaf(c3[2], ch, acc[14]);
            acc[15] = fmaf(c3[3], ch, acc[15]);
            acc[16] += ch;
        }
    }
    size_t ub = (size_t)(i - nbase) * 1088 + l;
#pragma unroll
    for (int c = 0; c < 17; ++c) {
        unsigned short hi = f2bf(acc[c]);
        Uhi[ub + c * 64] = hi;
        Ulo[ub + c * 64] = f2bf(acc[c] - bf2f(hi));
    }
}

// ---------------- ugemm: h_out = relu((U @ K2q)*invd + h_in@rootw + convb) ---
// 16 nodes/block (1250 blocks), 4 waves; wave w owns col-tile [w*16, w*16+16).
// k-loop FULLY unrolled: 136 straight-line loads (base + imm offsets <= 2112B)
// so the scheduler can hoist loads deep ahead of the serial MFMA chain.
// No LDS, no barrier; A (U) streams from HBM, B (K2q, 278 KB) L2-resident.
__global__ __launch_bounds__(256, 4) void ugemm_kernel(
    const unsigned short* __restrict__ Uhi, const unsigned short* __restrict__ Ulo,
    const unsigned short* __restrict__ K2qh, const unsigned short* __restrict__ K2ql,
    const unsigned short* __restrict__ Rqh, const unsigned short* __restrict__ Rql,
    const unsigned short* __restrict__ hhi_in, const unsigned short* __restrict__ hlo_in,
    const float* __restrict__ invd, const float* __restrict__ convb,
    float* __restrict__ h_out, unsigned short* __restrict__ hhi_out,
    unsigned short* __restrict__ hlo_out, int nbase, int nend)
{
    int w = threadIdx.x >> 6, l = threadIdx.x & 63;
    int quad = l >> 4, lr = l & 15;
    int n0 = nbase + blockIdx.x * 16;
    int row = n0 + lr;
    if (row > nend - 1) row = nend - 1;
    const unsigned short* pau = Uhi + (size_t)(row - nbase) * 1088 + quad * 8;
    const unsigned short* pal = Ulo + (size_t)(row - nbase) * 1088 + quad * 8;
    int o0 = w * 16 + lr;
    const unsigned short* pbh = K2qh + (size_t)o0 * 1088 + quad * 8;
    const unsigned short* pbl = K2ql + (size_t)o0 * 1088 + quad * 8;
    f32x4 a0 = {0.f, 0.f, 0.f, 0.f};
#pragma unroll
    for (int ks = 0; ks < 34; ++ks) {
        bf16x8 ah = *(const bf16x8*)(pau + ks * 32);
        bf16x8 av = *(const bf16x8*)(pal + ks * 32);
        bf16x8 bh = *(const bf16x8*)(pbh + ks * 32);
        bf16x8 bl = *(const bf16x8*)(pbl + ks * 32);
        a0 = __builtin_amdgcn_mfma_f32_16x16x32_bf16(ah, bh, a0, 0, 0, 0);
        a0 = __builtin_amdgcn_mfma_f32_16x16x32_bf16(ah, bl, a0, 0, 0, 0);
        a0 = __builtin_amdgcn_mfma_f32_16x16x32_bf16(av, bh, a0, 0, 0, 0);
    }
    // root term: h_in @ rootw (NOT divided by deg)
    f32x4 r0a = {0.f, 0.f, 0.f, 0.f};
    const unsigned short* prh = hhi_in + (size_t)row * 64 + quad * 8;
    const unsigned short* prl = hlo_in + (size_t)row * 64 + quad * 8;
#pragma unroll
    for (int ks = 0; ks < 2; ++ks) {
        bf16x8 ah = *(const bf16x8*)(prh + ks * 32);
        bf16x8 av = *(const bf16x8*)(prl + ks * 32);
        bf16x8 bh = *(const bf16x8*)(Rqh + (size_t)o0 * 64 + ks * 32 + quad * 8);
        bf16x8 bl = *(const bf16x8*)(Rql + (size_t)o0 * 64 + ks * 32 + quad * 8);
        r0a = __builtin_amdgcn_mfma_f32_16x16x32_bf16(ah, bh, r0a, 0, 0, 0);
        r0a = __builtin_amdgcn_mfma_f32_16x16x32_bf16(ah, bl, r0a, 0, 0, 0);
        r0a = __builtin_amdgcn_mfma_f32_16x16x32_bf16(av, bh, r0a, 0, 0, 0);
    }
    float cb0 = convb[o0];
    // C/D layout: col = lane&15 (-> o0), row = quad*4 + r
#pragma unroll
    for (int r = 0; r < 4; ++r) {
        int gn = n0 + quad * 4 + r;
        if (gn < nend) {
            float iv = invd[gn];
            size_t idx0 = (size_t)gn * 64 + o0;
            float v0 = fmaf(a0[r], iv, r0a[r] + cb0);
            v0 = fmaxf(v0, 0.f);
            h_out[idx0] = v0;
            unsigned short x0 = f2bf(v0);
            hhi_out[idx0] = x0;
            hlo_out[idx0] = f2bf(v0 - bf2f(x0));
        }
    }
}

// ---------------- out = h @ fc2_w + fc2_b ----------------
__global__ __launch_bounds__(256) void out_kernel(
    const float* __restrict__ h, const float* __restrict__ fc2_w,
    const float* __restrict__ fc2_b, float* __restrict__ out)
{
    int wave = blockIdx.x * 4 + (threadIdx.x >> 6);
    int lane = threadIdx.x & 63;
    float v = h[(size_t)wave * 64 + lane] * fc2_w[lane];
#pragma unroll
    for (int off = 32; off > 0; off >>= 1) v += __shfl_down(v, off);
    if (lane == 0) out[wave] = v + fc2_b[0];
}

extern "C" void kernel_launch(void* const* d_in, const int* in_sizes, int n_in,
                              void* d_out, int out_size, void* d_ws, size_t ws_size,
                              hipStream_t stream)
{
    const float* x         = (const float*)d_in[0];
    const int*   ei        = (const int*)  d_in[1];
    const float* edge_attr = (const float*)d_in[2];
    const float* fc1_w     = (const float*)d_in[3];
    const float* fc1_b     = (const float*)d_in[4];
    const float* k1_w      = (const float*)d_in[5];
    const float* k1_b      = (const float*)d_in[6];
    const float* k2_w      = (const float*)d_in[7];
    const float* k2_b      = (const float*)d_in[8];
    const float* root_w    = (const float*)d_in[9];
    const float* conv_b    = (const float*)d_in[10];
    const float* fc2_w     = (const float*)d_in[11];
    const float* fc2_b     = (const float*)d_in[12];
    float* out = (float*)d_out;

    // workspace layout, f32 units (all chunk sizes multiples of 4 -> 16B align)
    float* ws = (float*)d_ws;
    size_t off = 0;
    int* cnt   = (int*)(ws + off); off += 4 * NN;       // outc|inc|fs|fd
    int* outc  = cnt;
    int* inc   = cnt + NN;
    int* fd    = cnt + 3 * NN;
    int* rps   = (int*)(ws + off); off += 20004;
    int* rpd   = (int*)(ws + off); off += 20004;
    int* partials = (int*)(ws + off); off += 64;
    int* bases    = (int*)(ws + off); off += 64;
    int* smeta    = (int*)(ws + off); off += NE + 16;   // src node per dst-slot
    float* invd  = ws + off; off += NN;
    float* eks   = ws + off; off += (size_t)NE * 16;
    unsigned short* K2qh = (unsigned short*)(ws + off); off += 34816;  // 64x1088
    unsigned short* K2ql = (unsigned short*)(ws + off); off += 34816;
    unsigned short* Rqh  = (unsigned short*)(ws + off); off += 2048;   // 64x64
    unsigned short* Rql  = (unsigned short*)(ws + off); off += 2048;
    float* hA    = ws + off; off += (size_t)NN * WD;
    float* hB    = ws + off; off += (size_t)NN * WD;
    unsigned short* hhiA = (unsigned short*)(ws + off); off += (size_t)NN * 32;
    unsigned short* hloA = (unsigned short*)(ws + off); off += (size_t)NN * 32;
    unsigned short* hhiB = (unsigned short*)(ws + off); off += (size_t)NN * 32;
    unsigned short* hloB = (unsigned short*)(ws + off); off += (size_t)NN * 32;

    // U chunking (bf16 hi/lo planes, csz*1088 f32 units total)
    size_t totalf = ws_size / sizeof(float);
    size_t availf = totalf > off ? totalf - off : 0;
    const int divs[] = {1, 2, 4, 5, 8, 10, 20};
    int nch = 20;
    for (int di = 0; di < 7; ++di) {
        if (availf >= (size_t)(NN / divs[di]) * 1088) { nch = divs[di]; break; }
    }
    int csz = NN / nch;
    unsigned short* Uhi = (unsigned short*)(ws + off);
    unsigned short* Ulo = (unsigned short*)(ws + off + (size_t)csz * 544);

    hipMemsetAsync(cnt, 0, 4 * NN * sizeof(int), stream);
    count_kernel<<<(NE + 255) / 256, 256, 0, stream>>>(ei, outc, inc);
    scanA_kernel<<<40, 256, 0, stream>>>(cnt, partials);
    scanB_kernel<<<1, 64, 0, stream>>>(partials, bases);
    scanC_kernel<<<40, 256, 0, stream>>>(cnt, bases, rps, rpd, invd);
    ekfill_kernel<<<(NE + 255) / 256, 256, 0, stream>>>(ei, edge_attr, k1_w, k1_b,
                                                        rpd, fd, eks, smeta);
    gwt2_kernel<<<(64 * 1152 + 255) / 256, 256, 0, stream>>>(k2_w, k2_b, root_w,
                                                             K2qh, K2ql, Rqh, Rql);
    h0_kernel<<<(NN * WD + 255) / 256, 256, 0, stream>>>(x, fc1_w, fc1_b,
                                                         hA, hhiA, hloA);

    const float* hin = hA; float* hout = hB;
    const unsigned short* hhin = hhiA; const unsigned short* hloin = hloA;
    unsigned short* hhout = hhiB; unsigned short* hloout = hloB;
    for (int layer = 0; layer < DEPTH; ++layer) {
        for (int c = 0; c < nch; ++c) {
            int nb = c * csz, ne2 = nb + csz;
            ucomp_kernel<<<(csz + 3) / 4, 256, 0, stream>>>(
                hin, eks, smeta, rpd, Uhi, Ulo, nb, ne2);
            ugemm_kernel<<<(csz + 15) / 16, 256, 0, stream>>>(
                Uhi, Ulo, K2qh, K2ql, Rqh, Rql, hhin, hloin, invd, conv_b,
                hout, hhout, hloout, nb, ne2);
        }
        const float* t0 = hin; hin = hout; hout = (float*)t0;
        const unsigned short* t1 = hhin; hhin = hhout; hhout = (unsigned short*)t1;
        const unsigned short* t2 = hloin; hloin = hloout; hloout = (unsigned short*)t2;
    }

    out_kernel<<<NN / 4, 256, 0, stream>>>(hin, fc2_w, fc2_b, out);
}

// Round 7
// 741.056 us; speedup vs baseline: 1.1587x; 1.0213x over previous
//
#include <hip/hip_runtime.h>
#include <hip/hip_bf16.h>

// NNConv GNN, round 14: software-pipeline ugemm's k-loop (ucomp-style).
//  R13 post-mortem: full unroll + launch_bounds cap did NOT make the
//  compiler hoist loads — VGPR_Count=28, ~1 load in flight/wave (in-flight
//  arithmetic from 695 GB/s: ~1 KB/CU). Occupancy fix worked (16->37%).
//  ucomp proves the fix: its snapshot-then-prefetch loop sustains ~3 TB/s.
//  R14 ugemm: loop over 17 groups of 2 k-steps; ISSUE group g+1's 8 loads
//  (32 VGPR), then run group g's 6 MFMAs on snapshot regs. cur+next ~64
//  VGPR + acc/addr ~= 90, fits __launch_bounds__(256,4)'s 128 cap.
//  8 KB/wave in flight during compute -> HBM-saturating at ~12 waves/CU.
//  Everything else unchanged from R13.

#define NN 20000
#define NE 100000
#define WD 64
#define DEPTH 6

typedef __attribute__((ext_vector_type(8))) short bf16x8;
typedef __attribute__((ext_vector_type(4))) float f32x4;

__device__ __forceinline__ unsigned short f2bf(float v) {
    union { float f; unsigned u; } x; x.f = v;
    unsigned r = x.u + 0x7fffu + ((x.u >> 16) & 1u);
    return (unsigned short)(r >> 16);
}
__device__ __forceinline__ float bf2f(unsigned short b) {
    union { unsigned u; float f; } x; x.u = ((unsigned)b) << 16;
    return x.f;
}

// ---------------- per-node in/out degree counts ----------------
__global__ __launch_bounds__(256) void count_kernel(const int* __restrict__ ei,
                                                    int* __restrict__ outc,
                                                    int* __restrict__ inc)
{
    int e = blockIdx.x * 256 + threadIdx.x;
    if (e >= NE) return;
    atomicAdd(&outc[ei[e]], 1);
    atomicAdd(&inc[ei[NE + e]], 1);
}

// ---------------- hierarchical scan over [outc | inc] (40000 ints) ----------
__global__ __launch_bounds__(256) void scanA_kernel(const int* __restrict__ cnt,
                                                    int* __restrict__ partials)
{
    int b = blockIdx.x, t = threadIdx.x, lane = t & 63, w = t >> 6;
    int base = b * 1024 + t * 4;
    int s = 0;
#pragma unroll
    for (int i = 0; i < 4; ++i) {
        int idx = base + i;
        if (idx < 2 * NN) s += cnt[idx];
    }
#pragma unroll
    for (int off = 32; off > 0; off >>= 1) s += __shfl_down(s, off, 64);
    __shared__ int wsum[4];
    if (lane == 0) wsum[w] = s;
    __syncthreads();
    if (t == 0) partials[b] = wsum[0] + wsum[1] + wsum[2] + wsum[3];
}

__global__ __launch_bounds__(64) void scanB_kernel(const int* __restrict__ partials,
                                                   int* __restrict__ bases)
{
    int l = threadIdx.x;
    int p = (l < 40) ? partials[l] : 0;
    int v = p;
#pragma unroll
    for (int off = 1; off < 64; off <<= 1) {
        int u = __shfl_up(v, off, 64);
        if (l >= off) v += u;
    }
    if (l < 40) bases[l] = v - p;   // exclusive
}

__global__ __launch_bounds__(256) void scanC_kernel(const int* __restrict__ cnt,
                                                    const int* __restrict__ bases,
                                                    int* __restrict__ rps,
                                                    int* __restrict__ rpd,
                                                    float* __restrict__ invd)
{
    int b = blockIdx.x, t = threadIdx.x, lane = t & 63, w = t >> 6;
    int base = b * 1024 + t * 4;
    int v[4], s = 0;
#pragma unroll
    for (int i = 0; i < 4; ++i) {
        int idx = base + i;
        v[i] = (idx < 2 * NN) ? cnt[idx] : 0;
        s += v[i];
    }
    int tsum = s, sc = s;
#pragma unroll
    for (int off = 1; off < 64; off <<= 1) {
        int u = __shfl_up(sc, off, 64);
        if (lane >= off) sc += u;
    }
    __shared__ int wtot[4];
    if (lane == 63) wtot[w] = sc;
    __syncthreads();
    int wbase = 0;
    for (int j = 0; j < w; ++j) wbase += wtot[j];
    int run = bases[b] + wbase + sc - tsum;
#pragma unroll
    for (int i = 0; i < 4; ++i) {
        int idx = base + i;
        int e = run; run += v[i];
        if (idx < NN) {
            rps[idx] = e;
        } else if (idx < 2 * NN) {
            rpd[idx - NN] = e - NE;           // first-half total == NE
            invd[idx - NN] = 1.0f / fmaxf((float)v[i], 1.0f);
        }
    }
    if (b == 0 && t == 0) { rps[NN] = NE; rpd[NN] = NE; }
}

// ---------------- ek MLP into dst-CSR slots + src id per slot ----------------
__global__ __launch_bounds__(256) void ekfill_kernel(
    const int* __restrict__ ei, const float* __restrict__ ea,
    const float* __restrict__ k1w, const float* __restrict__ k1b,
    const int* __restrict__ rpd, int* __restrict__ fd,
    float* __restrict__ eks, int* __restrict__ smeta)
{
    int e = blockIdx.x * 256 + threadIdx.x;
    if (e >= NE) return;
    int s = ei[e], d = ei[NE + e];
    float a[6];
#pragma unroll
    for (int i = 0; i < 6; ++i) a[i] = ea[e * 6 + i];
    int slot_d = rpd[d] + atomicAdd(&fd[d], 1);
    smeta[slot_d] = s;                 // src node for this dst-CSR slot
#pragma unroll
    for (int j = 0; j < 16; ++j) {
        float v = k1b[j];
#pragma unroll
        for (int i = 0; i < 6; ++i) v = fmaf(a[i], k1w[i * 16 + j], v);
        eks[(size_t)slot_d * 16 + j] = fmaxf(v, 0.f);
    }
}

// ---------------- K2q[o][1088] / Rq[o][64] bf16 hi/lo (o-major for B-frags) --
__global__ __launch_bounds__(256) void gwt2_kernel(
    const float* __restrict__ k2w, const float* __restrict__ k2b,
    const float* __restrict__ rootw,
    unsigned short* __restrict__ K2qh, unsigned short* __restrict__ K2ql,
    unsigned short* __restrict__ Rqh, unsigned short* __restrict__ Rql)
{
    int idx = blockIdx.x * 256 + threadIdx.x;
    if (idx >= 64 * 1152) return;
    int o = idx / 1152, j = idx - o * 1152;
    float g;
    if (j < 1024)      { int c = j >> 6, k = j & 63; g = k2w[c * 4096 + k * 64 + o]; }
    else if (j < 1088) { int k = j - 1024;           g = k2b[k * 64 + o]; }
    else               { int k = j - 1088;           g = rootw[k * 64 + o]; }
    unsigned short hi = f2bf(g);
    unsigned short lo = f2bf(g - bf2f(hi));
    if (j < 1088) { K2qh[o * 1088 + j] = hi; K2ql[o * 1088 + j] = lo; }
    else { int k = j - 1088; Rqh[o * 64 + k] = hi; Rql[o * 64 + k] = lo; }
}

// ---------------- h0 = x*fc1_w + fc1_b -> f32 + hi/lo bf16 ----------------
__global__ __launch_bounds__(256) void h0_kernel(
    const float* __restrict__ x, const float* __restrict__ w,
    const float* __restrict__ b, float* __restrict__ h,
    unsigned short* __restrict__ hhi, unsigned short* __restrict__ hlo)
{
    int idx = blockIdx.x * 256 + threadIdx.x;
    if (idx >= NN * WD) return;
    int n = idx >> 6, o = idx & 63;
    float v = fmaf(x[n], w[o], b[o]);
    h[idx] = v;
    unsigned short hi = f2bf(v);
    hhi[idx] = hi;
    hlo[idx] = f2bf(v - bf2f(hi));
}

// ---------------- ucomp: U_i[c*64+k] = sum_e ek_e[c]*h[src_e][k]; strip16=sum h
// One wave per dst node; eks/smeta via wave-uniform scalar loads (1-deep
// prefetch); h row gather is a coalesced 256B load (h is 5 MB -> L2).
__global__ __launch_bounds__(256) void ucomp_kernel(
    const float* __restrict__ h, const float* __restrict__ eks,
    const int* __restrict__ smeta, const int* __restrict__ rpd,
    unsigned short* __restrict__ Uhi, unsigned short* __restrict__ Ulo,
    int nbase, int nend)
{
    int wv = threadIdx.x >> 6;
    int i = nbase + blockIdx.x * 4 + wv;
    if (i >= nend) return;
    int l = threadIdx.x & 63;
    float acc[17];
#pragma unroll
    for (int c = 0; c < 17; ++c) acc[c] = 0.f;
    int r0 = rpd[i], r1 = rpd[i + 1];
    if (r0 < r1) {
        int su = __builtin_amdgcn_readfirstlane(r0);
        float hv = h[(size_t)smeta[su] * 64 + l];
        const float* er = eks + (size_t)su * 16;
        f32x4 e0 = *(const f32x4*)(er);
        f32x4 e1 = *(const f32x4*)(er + 4);
        f32x4 e2 = *(const f32x4*)(er + 8);
        f32x4 e3 = *(const f32x4*)(er + 12);
        for (int s = r0; s < r1; ++s) {
            float ch = hv;
            f32x4 c0 = e0, c1 = e1, c2 = e2, c3 = e3;
            if (s + 1 < r1) {   // prefetch next edge during this edge's FMAs
                int s2 = __builtin_amdgcn_readfirstlane(s + 1);
                hv = h[(size_t)smeta[s2] * 64 + l];
                const float* er2 = eks + (size_t)s2 * 16;
                e0 = *(const f32x4*)(er2);
                e1 = *(const f32x4*)(er2 + 4);
                e2 = *(const f32x4*)(er2 + 8);
                e3 = *(const f32x4*)(er2 + 12);
            }
            acc[0]  = fmaf(c0[0], ch, acc[0]);
            acc[1]  = fmaf(c0[1], ch, acc[1]);
            acc[2]  = fmaf(c0[2], ch, acc[2]);
            acc[3]  = fmaf(c0[3], ch, acc[3]);
            acc[4]  = fmaf(c1[0], ch, acc[4]);
            acc[5]  = fmaf(c1[1], ch, acc[5]);
            acc[6]  = fmaf(c1[2], ch, acc[6]);
            acc[7]  = fmaf(c1[3], ch, acc[7]);
            acc[8]  = fmaf(c2[0], ch, acc[8]);
            acc[9]  = fmaf(c2[1], ch, acc[9]);
            acc[10] = fmaf(c2[2], ch, acc[10]);
            acc[11] = fmaf(c2[3], ch, acc[11]);
            acc[12] = fmaf(c3[0], ch, acc[12]);
            acc[13] = fmaf(c3[1], ch, acc[13]);
            acc[14] = fmaf(c3[2], ch, acc[14]);
            acc[15] = fmaf(c3[3], ch, acc[15]);
            acc[16] += ch;
        }
    }
    size_t ub = (size_t)(i - nbase) * 1088 + l;
#pragma unroll
    for (int c = 0; c < 17; ++c) {
        unsigned short hi = f2bf(acc[c]);
        Uhi[ub + c * 64] = hi;
        Ulo[ub + c * 64] = f2bf(acc[c] - bf2f(hi));
    }
}

// ---------------- ugemm: h_out = relu((U @ K2q)*invd + h_in@rootw + convb) ---
// 16 nodes/block (1250 blocks), 4 waves; wave w owns col-tile [w*16, w*16+16).
// k-loop software-pipelined ucomp-style: issue group g+1's 8 loads (32 VGPR),
// then run group g's 6 MFMAs on snapshot regs. 8 KB/wave in flight.
__global__ __launch_bounds__(256, 4) void ugemm_kernel(
    const unsigned short* __restrict__ Uhi, const unsigned short* __restrict__ Ulo,
    const unsigned short* __restrict__ K2qh, const unsigned short* __restrict__ K2ql,
    const unsigned short* __restrict__ Rqh, const unsigned short* __restrict__ Rql,
    const unsigned short* __restrict__ hhi_in, const unsigned short* __restrict__ hlo_in,
    const float* __restrict__ invd, const float* __restrict__ convb,
    float* __restrict__ h_out, unsigned short* __restrict__ hhi_out,
    unsigned short* __restrict__ hlo_out, int nbase, int nend)
{
    int w = threadIdx.x >> 6, l = threadIdx.x & 63;
    int quad = l >> 4, lr = l & 15;
    int n0 = nbase + blockIdx.x * 16;
    int row = n0 + lr;
    if (row > nend - 1) row = nend - 1;
    const unsigned short* pau = Uhi + (size_t)(row - nbase) * 1088 + quad * 8;
    const unsigned short* pal = Ulo + (size_t)(row - nbase) * 1088 + quad * 8;
    int o0 = w * 16 + lr;
    const unsigned short* pbh = K2qh + (size_t)o0 * 1088 + quad * 8;
    const unsigned short* pbl = K2ql + (size_t)o0 * 1088 + quad * 8;

    f32x4 a0 = {0.f, 0.f, 0.f, 0.f};
    // prologue: load group 0 (2 k-steps)
    bf16x8 cah0 = *(const bf16x8*)(pau);
    bf16x8 cav0 = *(const bf16x8*)(pal);
    bf16x8 cbh0 = *(const bf16x8*)(pbh);
    bf16x8 cbl0 = *(const bf16x8*)(pbl);
    bf16x8 cah1 = *(const bf16x8*)(pau + 32);
    bf16x8 cav1 = *(const bf16x8*)(pal + 32);
    bf16x8 cbh1 = *(const bf16x8*)(pbh + 32);
    bf16x8 cbl1 = *(const bf16x8*)(pbl + 32);
    for (int g = 0; g < 17; ++g) {
        // issue next group's loads BEFORE this group's MFMAs (ucomp pattern)
        if (g + 1 < 17) {
            int o = (g + 1) * 64;
            bf16x8 nah0 = *(const bf16x8*)(pau + o);
            bf16x8 nav0 = *(const bf16x8*)(pal + o);
            bf16x8 nbh0 = *(const bf16x8*)(pbh + o);
            bf16x8 nbl0 = *(const bf16x8*)(pbl + o);
            bf16x8 nah1 = *(const bf16x8*)(pau + o + 32);
            bf16x8 nav1 = *(const bf16x8*)(pal + o + 32);
            bf16x8 nbh1 = *(const bf16x8*)(pbh + o + 32);
            bf16x8 nbl1 = *(const bf16x8*)(pbl + o + 32);
            a0 = __builtin_amdgcn_mfma_f32_16x16x32_bf16(cah0, cbh0, a0, 0, 0, 0);
            a0 = __builtin_amdgcn_mfma_f32_16x16x32_bf16(cah0, cbl0, a0, 0, 0, 0);
            a0 = __builtin_amdgcn_mfma_f32_16x16x32_bf16(cav0, cbh0, a0, 0, 0, 0);
            a0 = __builtin_amdgcn_mfma_f32_16x16x32_bf16(cah1, cbh1, a0, 0, 0, 0);
            a0 = __builtin_amdgcn_mfma_f32_16x16x32_bf16(cah1, cbl1, a0, 0, 0, 0);
            a0 = __builtin_amdgcn_mfma_f32_16x16x32_bf16(cav1, cbh1, a0, 0, 0, 0);
            cah0 = nah0; cav0 = nav0; cbh0 = nbh0; cbl0 = nbl0;
            cah1 = nah1; cav1 = nav1; cbh1 = nbh1; cbl1 = nbl1;
        } else {
            a0 = __builtin_amdgcn_mfma_f32_16x16x32_bf16(cah0, cbh0, a0, 0, 0, 0);
            a0 = __builtin_amdgcn_mfma_f32_16x16x32_bf16(cah0, cbl0, a0, 0, 0, 0);
            a0 = __builtin_amdgcn_mfma_f32_16x16x32_bf16(cav0, cbh0, a0, 0, 0, 0);
            a0 = __builtin_amdgcn_mfma_f32_16x16x32_bf16(cah1, cbh1, a0, 0, 0, 0);
            a0 = __builtin_amdgcn_mfma_f32_16x16x32_bf16(cah1, cbl1, a0, 0, 0, 0);
            a0 = __builtin_amdgcn_mfma_f32_16x16x32_bf16(cav1, cbh1, a0, 0, 0, 0);
        }
    }
    // root term: h_in @ rootw (NOT divided by deg)
    f32x4 r0a = {0.f, 0.f, 0.f, 0.f};
    const unsigned short* prh = hhi_in + (size_t)row * 64 + quad * 8;
    const unsigned short* prl = hlo_in + (size_t)row * 64 + quad * 8;
#pragma unroll
    for (int ks = 0; ks < 2; ++ks) {
        bf16x8 ah = *(const bf16x8*)(prh + ks * 32);
        bf16x8 av = *(const bf16x8*)(prl + ks * 32);
        bf16x8 bh = *(const bf16x8*)(Rqh + (size_t)o0 * 64 + ks * 32 + quad * 8);
        bf16x8 bl = *(const bf16x8*)(Rql + (size_t)o0 * 64 + ks * 32 + quad * 8);
        r0a = __builtin_amdgcn_mfma_f32_16x16x32_bf16(ah, bh, r0a, 0, 0, 0);
        r0a = __builtin_amdgcn_mfma_f32_16x16x32_bf16(ah, bl, r0a, 0, 0, 0);
        r0a = __builtin_amdgcn_mfma_f32_16x16x32_bf16(av, bh, r0a, 0, 0, 0);
    }
    float cb0 = convb[o0];
    // C/D layout: col = lane&15 (-> o0), row = quad*4 + r
#pragma unroll
    for (int r = 0; r < 4; ++r) {
        int gn = n0 + quad * 4 + r;
        if (gn < nend) {
            float iv = invd[gn];
            size_t idx0 = (size_t)gn * 64 + o0;
            float v0 = fmaf(a0[r], iv, r0a[r] + cb0);
            v0 = fmaxf(v0, 0.f);
            h_out[idx0] = v0;
            unsigned short x0 = f2bf(v0);
            hhi_out[idx0] = x0;
            hlo_out[idx0] = f2bf(v0 - bf2f(x0));
        }
    }
}

// ---------------- out = h @ fc2_w + fc2_b ----------------
__global__ __launch_bounds__(256) void out_kernel(
    const float* __restrict__ h, const float* __restrict__ fc2_w,
    const float* __restrict__ fc2_b, float* __restrict__ out)
{
    int wave = blockIdx.x * 4 + (threadIdx.x >> 6);
    int lane = threadIdx.x & 63;
    float v = h[(size_t)wave * 64 + lane] * fc2_w[lane];
#pragma unroll
    for (int off = 32; off > 0; off >>= 1) v += __shfl_down(v, off);
    if (lane == 0) out[wave] = v + fc2_b[0];
}

extern "C" void kernel_launch(void* const* d_in, const int* in_sizes, int n_in,
                              void* d_out, int out_size, void* d_ws, size_t ws_size,
                              hipStream_t stream)
{
    const float* x         = (const float*)d_in[0];
    const int*   ei        = (const int*)  d_in[1];
    const float* edge_attr = (const float*)d_in[2];
    const float* fc1_w     = (const float*)d_in[3];
    const float* fc1_b     = (const float*)d_in[4];
    const float* k1_w      = (const float*)d_in[5];
    const float* k1_b      = (const float*)d_in[6];
    const float* k2_w      = (const float*)d_in[7];
    const float* k2_b      = (const float*)d_in[8];
    const float* root_w    = (const float*)d_in[9];
    const float* conv_b    = (const float*)d_in[10];
    const float* fc2_w     = (const float*)d_in[11];
    const float* fc2_b     = (const float*)d_in[12];
    float* out = (float*)d_out;

    // workspace layout, f32 units (all chunk sizes multiples of 4 -> 16B align)
    float* ws = (float*)d_ws;
    size_t off = 0;
    int* cnt   = (int*)(ws + off); off += 4 * NN;       // outc|inc|fs|fd
    int* outc  = cnt;
    int* inc   = cnt + NN;
    int* fd    = cnt + 3 * NN;
    int* rps   = (int*)(ws + off); off += 20004;
    int* rpd   = (int*)(ws + off); off += 20004;
    int* partials = (int*)(ws + off); off += 64;
    int* bases    = (int*)(ws + off); off += 64;
    int* smeta    = (int*)(ws + off); off += NE + 16;   // src node per dst-slot
    float* invd  = ws + off; off += NN;
    float* eks   = ws + off; off += (size_t)NE * 16;
    unsigned short* K2qh = (unsigned short*)(ws + off); off += 34816;  // 64x1088
    unsigned short* K2ql = (unsigned short*)(ws + off); off += 34816;
    unsigned short* Rqh  = (unsigned short*)(ws + off); off += 2048;   // 64x64
    unsigned short* Rql  = (unsigned short*)(ws + off); off += 2048;
    float* hA    = ws + off; off += (size_t)NN * WD;
    float* hB    = ws + off; off += (size_t)NN * WD;
    unsigned short* hhiA = (unsigned short*)(ws + off); off += (size_t)NN * 32;
    unsigned short* hloA = (unsigned short*)(ws + off); off += (size_t)NN * 32;
    unsigned short* hhiB = (unsigned short*)(ws + off); off += (size_t)NN * 32;
    unsigned short* hloB = (unsigned short*)(ws + off); off += (size_t)NN * 32;

    // U chunking (bf16 hi/lo planes, csz*1088 f32 units total)
    size_t totalf = ws_size / sizeof(float);
    size_t availf = totalf > off ? totalf - off : 0;
    const int divs[] = {1, 2, 4, 5, 8, 10, 20};
    int nch = 20;
    for (int di = 0; di < 7; ++di) {
        if (availf >= (size_t)(NN / divs[di]) * 1088) { nch = divs[di]; break; }
    }
    int csz = NN / nch;
    unsigned short* Uhi = (unsigned short*)(ws + off);
    unsigned short* Ulo = (unsigned short*)(ws + off + (size_t)csz * 544);

    hipMemsetAsync(cnt, 0, 4 * NN * sizeof(int), stream);
    count_kernel<<<(NE + 255) / 256, 256, 0, stream>>>(ei, outc, inc);
    scanA_kernel<<<40, 256, 0, stream>>>(cnt, partials);
    scanB_kernel<<<1, 64, 0, stream>>>(partials, bases);
    scanC_kernel<<<40, 256, 0, stream>>>(cnt, bases, rps, rpd, invd);
    ekfill_kernel<<<(NE + 255) / 256, 256, 0, stream>>>(ei, edge_attr, k1_w, k1_b,
                                                        rpd, fd, eks, smeta);
    gwt2_kernel<<<(64 * 1152 + 255) / 256, 256, 0, stream>>>(k2_w, k2_b, root_w,
                                                             K2qh, K2ql, Rqh, Rql);
    h0_kernel<<<(NN * WD + 255) / 256, 256, 0, stream>>>(x, fc1_w, fc1_b,
                                                         hA, hhiA, hloA);

    const float* hin = hA; float* hout = hB;
    const unsigned short* hhin = hhiA; const unsigned short* hloin = hloA;
    unsigned short* hhout = hhiB; unsigned short* hloout = hloB;
    for (int layer = 0; layer < DEPTH; ++layer) {
        for (int c = 0; c < nch; ++c) {
            int nb = c * csz, ne2 = nb + csz;
            ucomp_kernel<<<(csz + 3) / 4, 256, 0, stream>>>(
                hin, eks, smeta, rpd, Uhi, Ulo, nb, ne2);
            ugemm_kernel<<<(csz + 15) / 16, 256, 0, stream>>>(
                Uhi, Ulo, K2qh, K2ql, Rqh, Rql, hhin, hloin, invd, conv_b,
                hout, hhout, hloout, nb, ne2);
        }
        const float* t0 = hin; hin = hout; hout = (float*)t0;
        const unsigned short* t1 = hhin; hhin = hhout; hhout = (unsigned short*)t1;
        const unsigned short* t2 = hloin; hloin = hloout; hloout = (unsigned short*)t2;
    }

    out_kernel<<<NN / 4, 256, 0, stream>>>(hin, fc2_w, fc2_b, out);
}

// Round 8
// 565.746 us; speedup vs baseline: 1.5177x; 1.3099x over previous
//
#include <hip/hip_runtime.h>
#include <hip/hip_bf16.h>

// NNConv GNN, round 15: ugemm via global_load_lds double-buffered staging.
//  R13/R14 post-mortem: hipcc sinks plain vector loads to their uses
//  (VGPR 28-32 both rounds, <1 load in flight/wave, 693 GB/s) regardless of
//  source-level pipelining. The only scheduler-proof MLP mechanism is
//  __builtin_amdgcn_global_load_lds (fire-and-forget DMA, no dest VGPR;
//  drained by the vmcnt(0) the compiler emits at __syncthreads — m97
//  pattern). R15 ugemm: 32x64 tile, 8 waves (2 rg x 4 ct), BK=64, 17
//  chunks, 2-phase double-buffer (stage c+1 into buf^1 while computing c).
//  LDS chunk-major [g][half][row][8]: unit index linear in tid (satisfies
//  the wave-uniform-base+lane*16 DMA constraint by construction), 16 B
//  contiguous global sources from the EXISTING Uhi/Ulo/K2q layouts, and
//  conflict-free (8 words/bank minimum) ds_read_b128s. 48 KB LDS -> 3
//  blocks/CU; grid 625. MFMA order identical to R14 (bitwise-same result).
//  Everything outside ugemm is byte-identical to R14.

#define NN 20000
#define NE 100000
#define WD 64
#define DEPTH 6

typedef __attribute__((ext_vector_type(8))) short bf16x8;
typedef __attribute__((ext_vector_type(4))) float f32x4;

typedef __attribute__((address_space(1))) const void gvoid;
typedef __attribute__((address_space(3))) void lvoid;
__device__ __forceinline__ void gl_lds16(const void* g, void* l) {
    __builtin_amdgcn_global_load_lds((gvoid*)g, (lvoid*)l, 16, 0, 0);
}

__device__ __forceinline__ unsigned short f2bf(float v) {
    union { float f; unsigned u; } x; x.f = v;
    unsigned r = x.u + 0x7fffu + ((x.u >> 16) & 1u);
    return (unsigned short)(r >> 16);
}
__device__ __forceinline__ float bf2f(unsigned short b) {
    union { unsigned u; float f; } x; x.u = ((unsigned)b) << 16;
    return x.f;
}

// ---------------- per-node in/out degree counts ----------------
__global__ __launch_bounds__(256) void count_kernel(const int* __restrict__ ei,
                                                    int* __restrict__ outc,
                                                    int* __restrict__ inc)
{
    int e = blockIdx.x * 256 + threadIdx.x;
    if (e >= NE) return;
    atomicAdd(&outc[ei[e]], 1);
    atomicAdd(&inc[ei[NE + e]], 1);
}

// ---------------- hierarchical scan over [outc | inc] (40000 ints) ----------
__global__ __launch_bounds__(256) void scanA_kernel(const int* __restrict__ cnt,
                                                    int* __restrict__ partials)
{
    int b = blockIdx.x, t = threadIdx.x, lane = t & 63, w = t >> 6;
    int base = b * 1024 + t * 4;
    int s = 0;
#pragma unroll
    for (int i = 0; i < 4; ++i) {
        int idx = base + i;
        if (idx < 2 * NN) s += cnt[idx];
    }
#pragma unroll
    for (int off = 32; off > 0; off >>= 1) s += __shfl_down(s, off, 64);
    __shared__ int wsum[4];
    if (lane == 0) wsum[w] = s;
    __syncthreads();
    if (t == 0) partials[b] = wsum[0] + wsum[1] + wsum[2] + wsum[3];
}

__global__ __launch_bounds__(64) void scanB_kernel(const int* __restrict__ partials,
                                                   int* __restrict__ bases)
{
    int l = threadIdx.x;
    int p = (l < 40) ? partials[l] : 0;
    int v = p;
#pragma unroll
    for (int off = 1; off < 64; off <<= 1) {
        int u = __shfl_up(v, off, 64);
        if (l >= off) v += u;
    }
    if (l < 40) bases[l] = v - p;   // exclusive
}

__global__ __launch_bounds__(256) void scanC_kernel(const int* __restrict__ cnt,
                                                    const int* __restrict__ bases,
                                                    int* __restrict__ rps,
                                                    int* __restrict__ rpd,
                                                    float* __restrict__ invd)
{
    int b = blockIdx.x, t = threadIdx.x, lane = t & 63, w = t >> 6;
    int base = b * 1024 + t * 4;
    int v[4], s = 0;
#pragma unroll
    for (int i = 0; i < 4; ++i) {
        int idx = base + i;
        v[i] = (idx < 2 * NN) ? cnt[idx] : 0;
        s += v[i];
    }
    int tsum = s, sc = s;
#pragma unroll
    for (int off = 1; off < 64; off <<= 1) {
        int u = __shfl_up(sc, off, 64);
        if (lane >= off) sc += u;
    }
    __shared__ int wtot[4];
    if (lane == 63) wtot[w] = sc;
    __syncthreads();
    int wbase = 0;
    for (int j = 0; j < w; ++j) wbase += wtot[j];
    int run = bases[b] + wbase + sc - tsum;
#pragma unroll
    for (int i = 0; i < 4; ++i) {
        int idx = base + i;
        int e = run; run += v[i];
        if (idx < NN) {
            rps[idx] = e;
        } else if (idx < 2 * NN) {
            rpd[idx - NN] = e - NE;           // first-half total == NE
            invd[idx - NN] = 1.0f / fmaxf((float)v[i], 1.0f);
        }
    }
    if (b == 0 && t == 0) { rps[NN] = NE; rpd[NN] = NE; }
}

// ---------------- ek MLP into dst-CSR slots + src id per slot ----------------
__global__ __launch_bounds__(256) void ekfill_kernel(
    const int* __restrict__ ei, const float* __restrict__ ea,
    const float* __restrict__ k1w, const float* __restrict__ k1b,
    const int* __restrict__ rpd, int* __restrict__ fd,
    float* __restrict__ eks, int* __restrict__ smeta)
{
    int e = blockIdx.x * 256 + threadIdx.x;
    if (e >= NE) return;
    int s = ei[e], d = ei[NE + e];
    float a[6];
#pragma unroll
    for (int i = 0; i < 6; ++i) a[i] = ea[e * 6 + i];
    int slot_d = rpd[d] + atomicAdd(&fd[d], 1);
    smeta[slot_d] = s;                 // src node for this dst-CSR slot
#pragma unroll
    for (int j = 0; j < 16; ++j) {
        float v = k1b[j];
#pragma unroll
        for (int i = 0; i < 6; ++i) v = fmaf(a[i], k1w[i * 16 + j], v);
        eks[(size_t)slot_d * 16 + j] = fmaxf(v, 0.f);
    }
}

// ---------------- K2q[o][1088] / Rq[o][64] bf16 hi/lo (o-major for B-frags) --
__global__ __launch_bounds__(256) void gwt2_kernel(
    const float* __restrict__ k2w, const float* __restrict__ k2b,
    const float* __restrict__ rootw,
    unsigned short* __restrict__ K2qh, unsigned short* __restrict__ K2ql,
    unsigned short* __restrict__ Rqh, unsigned short* __restrict__ Rql)
{
    int idx = blockIdx.x * 256 + threadIdx.x;
    if (idx >= 64 * 1152) return;
    int o = idx / 1152, j = idx - o * 1152;
    float g;
    if (j < 1024)      { int c = j >> 6, k = j & 63; g = k2w[c * 4096 + k * 64 + o]; }
    else if (j < 1088) { int k = j - 1024;           g = k2b[k * 64 + o]; }
    else               { int k = j - 1088;           g = rootw[k * 64 + o]; }
    unsigned short hi = f2bf(g);
    unsigned short lo = f2bf(g - bf2f(hi));
    if (j < 1088) { K2qh[o * 1088 + j] = hi; K2ql[o * 1088 + j] = lo; }
    else { int k = j - 1088; Rqh[o * 64 + k] = hi; Rql[o * 64 + k] = lo; }
}

// ---------------- h0 = x*fc1_w + fc1_b -> f32 + hi/lo bf16 ----------------
__global__ __launch_bounds__(256) void h0_kernel(
    const float* __restrict__ x, const float* __restrict__ w,
    const float* __restrict__ b, float* __restrict__ h,
    unsigned short* __restrict__ hhi, unsigned short* __restrict__ hlo)
{
    int idx = blockIdx.x * 256 + threadIdx.x;
    if (idx >= NN * WD) return;
    int n = idx >> 6, o = idx & 63;
    float v = fmaf(x[n], w[o], b[o]);
    h[idx] = v;
    unsigned short hi = f2bf(v);
    hhi[idx] = hi;
    hlo[idx] = f2bf(v - bf2f(hi));
}

// ---------------- ucomp: U_i[c*64+k] = sum_e ek_e[c]*h[src_e][k]; strip16=sum h
// One wave per dst node; eks/smeta via wave-uniform scalar loads (1-deep
// prefetch); h row gather is a coalesced 256B load (h is 5 MB -> L2).
__global__ __launch_bounds__(256) void ucomp_kernel(
    const float* __restrict__ h, const float* __restrict__ eks,
    const int* __restrict__ smeta, const int* __restrict__ rpd,
    unsigned short* __restrict__ Uhi, unsigned short* __restrict__ Ulo,
    int nbase, int nend)
{
    int wv = threadIdx.x >> 6;
    int i = nbase + blockIdx.x * 4 + wv;
    if (i >= nend) return;
    int l = threadIdx.x & 63;
    float acc[17];
#pragma unroll
    for (int c = 0; c < 17; ++c) acc[c] = 0.f;
    int r0 = rpd[i], r1 = rpd[i + 1];
    if (r0 < r1) {
        int su = __builtin_amdgcn_readfirstlane(r0);
        float hv = h[(size_t)smeta[su] * 64 + l];
        const float* er = eks + (size_t)su * 16;
        f32x4 e0 = *(const f32x4*)(er);
        f32x4 e1 = *(const f32x4*)(er + 4);
        f32x4 e2 = *(const f32x4*)(er + 8);
        f32x4 e3 = *(const f32x4*)(er + 12);
        for (int s = r0; s < r1; ++s) {
            float ch = hv;
            f32x4 c0 = e0, c1 = e1, c2 = e2, c3 = e3;
            if (s + 1 < r1) {   // prefetch next edge during this edge's FMAs
                int s2 = __builtin_amdgcn_readfirstlane(s + 1);
                hv = h[(size_t)smeta[s2] * 64 + l];
                const float* er2 = eks + (size_t)s2 * 16;
                e0 = *(const f32x4*)(er2);
                e1 = *(const f32x4*)(er2 + 4);
                e2 = *(const f32x4*)(er2 + 8);
                e3 = *(const f32x4*)(er2 + 12);
            }
            acc[0]  = fmaf(c0[0], ch, acc[0]);
            acc[1]  = fmaf(c0[1], ch, acc[1]);
            acc[2]  = fmaf(c0[2], ch, acc[2]);
            acc[3]  = fmaf(c0[3], ch, acc[3]);
            acc[4]  = fmaf(c1[0], ch, acc[4]);
            acc[5]  = fmaf(c1[1], ch, acc[5]);
            acc[6]  = fmaf(c1[2], ch, acc[6]);
            acc[7]  = fmaf(c1[3], ch, acc[7]);
            acc[8]  = fmaf(c2[0], ch, acc[8]);
            acc[9]  = fmaf(c2[1], ch, acc[9]);
            acc[10] = fmaf(c2[2], ch, acc[10]);
            acc[11] = fmaf(c2[3], ch, acc[11]);
            acc[12] = fmaf(c3[0], ch, acc[12]);
            acc[13] = fmaf(c3[1], ch, acc[13]);
            acc[14] = fmaf(c3[2], ch, acc[14]);
            acc[15] = fmaf(c3[3], ch, acc[15]);
            acc[16] += ch;
        }
    }
    size_t ub = (size_t)(i - nbase) * 1088 + l;
#pragma unroll
    for (int c = 0; c < 17; ++c) {
        unsigned short hi = f2bf(acc[c]);
        Uhi[ub + c * 64] = hi;
        Ulo[ub + c * 64] = f2bf(acc[c] - bf2f(hi));
    }
}

// ---------------- ugemm: h_out = relu((U @ K2q)*invd + h_in@rootw + convb) ---
// 32 rows x 64 cols per block, 8 waves = 2 row-groups x 4 col-tiles.
// K split into 17 chunks of 64; each chunk's A (8 KB) and B (16 KB) staged
// into LDS via global_load_lds (fire-and-forget DMA), double-buffered:
// stage chunk c+1 into buf^1 while computing chunk c from buf. One
// __syncthreads per chunk (its implicit vmcnt(0) drain publishes buf^1).
// LDS layout [g][half][row][8] -> staging unit index is linear in tid
// (wave-uniform base + lane*16 satisfied), global sources are contiguous
// 16 B slices of the existing Uhi/Ulo/K2q layouts, ds_reads conflict-free.
__global__ __launch_bounds__(512, 6) void ugemm_kernel(
    const unsigned short* __restrict__ Uhi, const unsigned short* __restrict__ Ulo,
    const unsigned short* __restrict__ K2qh, const unsigned short* __restrict__ K2ql,
    const unsigned short* __restrict__ Rqh, const unsigned short* __restrict__ Rql,
    const unsigned short* __restrict__ hhi_in, const unsigned short* __restrict__ hlo_in,
    const float* __restrict__ invd, const float* __restrict__ convb,
    float* __restrict__ h_out, unsigned short* __restrict__ hhi_out,
    unsigned short* __restrict__ hlo_out, int nbase, int nend)
{
    __shared__ __align__(16) unsigned short Asm[2][8][2][32][8];  // 16 KB
    __shared__ __align__(16) unsigned short Bsm[2][8][2][64][8];  // 32 KB
    int tid = threadIdx.x;
    int w = tid >> 6, l = tid & 63;
    int quad = l >> 4, lr = l & 15;
    int rg = w >> 2, ct = w & 3;
    int n0 = nbase + blockIdx.x * 32;
    int n0l = n0 - nbase;
    int ncl = nend - nbase;

    // per-thread staging coordinates (fixed; source advances 64 elems/chunk)
    int ga = tid >> 6, ha = (tid >> 5) & 1, ra = tid & 31;       // A unit
    int rla = n0l + ra; if (rla >= ncl) rla = ncl - 1;
    const unsigned short* asrc = (ha ? Ulo : Uhi) + (size_t)rla * 1088 + ga * 8;
    int gb0 = tid >> 7, hb0 = (tid >> 6) & 1, ob0 = tid & 63;    // B units
    int ub1 = 512 + tid;
    int gb1 = ub1 >> 7, hb1 = (ub1 >> 6) & 1, ob1 = ub1 & 63;
    const unsigned short* bsrc0 = (hb0 ? K2ql : K2qh) + (size_t)ob0 * 1088 + gb0 * 8;
    const unsigned short* bsrc1 = (hb1 ? K2ql : K2qh) + (size_t)ob1 * 1088 + gb1 * 8;

    // prologue: stage chunk 0 into buf 0
    gl_lds16(asrc, (void*)&Asm[0][ga][ha][ra][0]);
    gl_lds16(bsrc0, (void*)&Bsm[0][gb0][hb0][ob0][0]);
    gl_lds16(bsrc1, (void*)&Bsm[0][gb1][hb1][ob1][0]);
    __syncthreads();

    int r = rg * 16 + lr;       // A row within tile
    int o = ct * 16 + lr;       // output col
    f32x4 acc = {0.f, 0.f, 0.f, 0.f};
    int cur = 0;
    for (int c = 0; c < 17; ++c) {
        if (c + 1 < 17) {       // stage next chunk into the other buffer
            int koff = (c + 1) * 64;
            int nb = cur ^ 1;
            gl_lds16(asrc + koff, (void*)&Asm[nb][ga][ha][ra][0]);
            gl_lds16(bsrc0 + koff, (void*)&Bsm[nb][gb0][hb0][ob0][0]);
            gl_lds16(bsrc1 + koff, (void*)&Bsm[nb][gb1][hb1][ob1][0]);
        }
#pragma unroll
        for (int kk = 0; kk < 2; ++kk) {
            int g = kk * 4 + quad;
            bf16x8 ah = *(const bf16x8*)&Asm[cur][g][0][r][0];
            bf16x8 av = *(const bf16x8*)&Asm[cur][g][1][r][0];
            bf16x8 bh = *(const bf16x8*)&Bsm[cur][g][0][o][0];
            bf16x8 bl = *(const bf16x8*)&Bsm[cur][g][1][o][0];
            acc = __builtin_amdgcn_mfma_f32_16x16x32_bf16(ah, bh, acc, 0, 0, 0);
            acc = __builtin_amdgcn_mfma_f32_16x16x32_bf16(ah, bl, acc, 0, 0, 0);
            acc = __builtin_amdgcn_mfma_f32_16x16x32_bf16(av, bh, acc, 0, 0, 0);
        }
        __syncthreads();        // drains vmcnt (staging) + lgkm; publishes buf^1
        cur ^= 1;
    }

    // root term: h_in @ rootw (NOT divided by deg)
    int row = n0 + rg * 16 + lr;
    if (row > nend - 1) row = nend - 1;
    f32x4 r0a = {0.f, 0.f, 0.f, 0.f};
    const unsigned short* prh = hhi_in + (size_t)row * 64 + quad * 8;
    const unsigned short* prl = hlo_in + (size_t)row * 64 + quad * 8;
#pragma unroll
    for (int ks = 0; ks < 2; ++ks) {
        bf16x8 ah = *(const bf16x8*)(prh + ks * 32);
        bf16x8 av = *(const bf16x8*)(prl + ks * 32);
        bf16x8 bh = *(const bf16x8*)(Rqh + (size_t)o * 64 + ks * 32 + quad * 8);
        bf16x8 bl = *(const bf16x8*)(Rql + (size_t)o * 64 + ks * 32 + quad * 8);
        r0a = __builtin_amdgcn_mfma_f32_16x16x32_bf16(ah, bh, r0a, 0, 0, 0);
        r0a = __builtin_amdgcn_mfma_f32_16x16x32_bf16(ah, bl, r0a, 0, 0, 0);
        r0a = __builtin_amdgcn_mfma_f32_16x16x32_bf16(av, bh, r0a, 0, 0, 0);
    }
    float cb0 = convb[o];
    // C/D layout: col = lane&15 (-> o), row = quad*4 + rr
#pragma unroll
    for (int rr = 0; rr < 4; ++rr) {
        int gn = n0 + rg * 16 + quad * 4 + rr;
        if (gn < nend) {
            float iv = invd[gn];
            size_t idx0 = (size_t)gn * 64 + o;
            float v0 = fmaf(acc[rr], iv, r0a[rr] + cb0);
            v0 = fmaxf(v0, 0.f);
            h_out[idx0] = v0;
            unsigned short x0 = f2bf(v0);
            hhi_out[idx0] = x0;
            hlo_out[idx0] = f2bf(v0 - bf2f(x0));
        }
    }
}

// ---------------- out = h @ fc2_w + fc2_b ----------------
__global__ __launch_bounds__(256) void out_kernel(
    const float* __restrict__ h, const float* __restrict__ fc2_w,
    const float* __restrict__ fc2_b, float* __restrict__ out)
{
    int wave = blockIdx.x * 4 + (threadIdx.x >> 6);
    int lane = threadIdx.x & 63;
    float v = h[(size_t)wave * 64 + lane] * fc2_w[lane];
#pragma unroll
    for (int off = 32; off > 0; off >>= 1) v += __shfl_down(v, off);
    if (lane == 0) out[wave] = v + fc2_b[0];
}

extern "C" void kernel_launch(void* const* d_in, const int* in_sizes, int n_in,
                              void* d_out, int out_size, void* d_ws, size_t ws_size,
                              hipStream_t stream)
{
    const float* x         = (const float*)d_in[0];
    const int*   ei        = (const int*)  d_in[1];
    const float* edge_attr = (const float*)d_in[2];
    const float* fc1_w     = (const float*)d_in[3];
    const float* fc1_b     = (const float*)d_in[4];
    const float* k1_w      = (const float*)d_in[5];
    const float* k1_b      = (const float*)d_in[6];
    const float* k2_w      = (const float*)d_in[7];
    const float* k2_b      = (const float*)d_in[8];
    const float* root_w    = (const float*)d_in[9];
    const float* conv_b    = (const float*)d_in[10];
    const float* fc2_w     = (const float*)d_in[11];
    const float* fc2_b     = (const float*)d_in[12];
    float* out = (float*)d_out;

    // workspace layout, f32 units (all chunk sizes multiples of 4 -> 16B align)
    float* ws = (float*)d_ws;
    size_t off = 0;
    int* cnt   = (int*)(ws + off); off += 4 * NN;       // outc|inc|fs|fd
    int* outc  = cnt;
    int* inc   = cnt + NN;
    int* fd    = cnt + 3 * NN;
    int* rps   = (int*)(ws + off); off += 20004;
    int* rpd   = (int*)(ws + off); off += 20004;
    int* partials = (int*)(ws + off); off += 64;
    int* bases    = (int*)(ws + off); off += 64;
    int* smeta    = (int*)(ws + off); off += NE + 16;   // src node per dst-slot
    float* invd  = ws + off; off += NN;
    float* eks   = ws + off; off += (size_t)NE * 16;
    unsigned short* K2qh = (unsigned short*)(ws + off); off += 34816;  // 64x1088
    unsigned short* K2ql = (unsigned short*)(ws + off); off += 34816;
    unsigned short* Rqh  = (unsigned short*)(ws + off); off += 2048;   // 64x64
    unsigned short* Rql  = (unsigned short*)(ws + off); off += 2048;
    float* hA    = ws + off; off += (size_t)NN * WD;
    float* hB    = ws + off; off += (size_t)NN * WD;
    unsigned short* hhiA = (unsigned short*)(ws + off); off += (size_t)NN * 32;
    unsigned short* hloA = (unsigned short*)(ws + off); off += (size_t)NN * 32;
    unsigned short* hhiB = (unsigned short*)(ws + off); off += (size_t)NN * 32;
    unsigned short* hloB = (unsigned short*)(ws + off); off += (size_t)NN * 32;

    // U chunking (bf16 hi/lo planes, csz*1088 f32 units total)
    size_t totalf = ws_size / sizeof(float);
    size_t availf = totalf > off ? totalf - off : 0;
    const int divs[] = {1, 2, 4, 5, 8, 10, 20};
    int nch = 20;
    for (int di = 0; di < 7; ++di) {
        if (availf >= (size_t)(NN / divs[di]) * 1088) { nch = divs[di]; break; }
    }
    int csz = NN / nch;
    unsigned short* Uhi = (unsigned short*)(ws + off);
    unsigned short* Ulo = (unsigned short*)(ws + off + (size_t)csz * 544);

    hipMemsetAsync(cnt, 0, 4 * NN * sizeof(int), stream);
    count_kernel<<<(NE + 255) / 256, 256, 0, stream>>>(ei, outc, inc);
    scanA_kernel<<<40, 256, 0, stream>>>(cnt, partials);
    scanB_kernel<<<1, 64, 0, stream>>>(partials, bases);
    scanC_kernel<<<40, 256, 0, stream>>>(cnt, bases, rps, rpd, invd);
    ekfill_kernel<<<(NE + 255) / 256, 256, 0, stream>>>(ei, edge_attr, k1_w, k1_b,
                                                        rpd, fd, eks, smeta);
    gwt2_kernel<<<(64 * 1152 + 255) / 256, 256, 0, stream>>>(k2_w, k2_b, root_w,
                                                             K2qh, K2ql, Rqh, Rql);
    h0_kernel<<<(NN * WD + 255) / 256, 256, 0, stream>>>(x, fc1_w, fc1_b,
                                                         hA, hhiA, hloA);

    const float* hin = hA; float* hout = hB;
    const unsigned short* hhin = hhiA; const unsigned short* hloin = hloA;
    unsigned short* hhout = hhiB; unsigned short* hloout = hloB;
    for (int layer = 0; layer < DEPTH; ++layer) {
        for (int c = 0; c < nch; ++c) {
            int nb = c * csz, ne2 = nb + csz;
            ucomp_kernel<<<(csz + 3) / 4, 256, 0, stream>>>(
                hin, eks, smeta, rpd, Uhi, Ulo, nb, ne2);
            ugemm_kernel<<<(csz + 31) / 32, 512, 0, stream>>>(
                Uhi, Ulo, K2qh, K2ql, Rqh, Rql, hhin, hloin, invd, conv_b,
                hout, hhout, hloout, nb, ne2);
        }
        const float* t0 = hin; hin = hout; hout = (float*)t0;
        const unsigned short* t1 = hhin; hhin = hhout; hhout = (unsigned short*)t1;
        const unsigned short* t2 = hloin; hloin = hloout; hloout = (unsigned short*)t2;
    }

    out_kernel<<<NN / 4, 256, 0, stream>>>(hin, fc2_w, fc2_b, out);
}